// Round 9
// baseline (468.500 us; speedup 1.0000x reference)
//
#include <hip/hip_runtime.h>
#include <hip/hip_bf16.h>
#include <stdint.h>

#define NN 3072
#define EE 49152
#define DD 256
#define OO 512
#define HH 8
#define DHH 32
#define NETT 5
#define NC 8
#define NCMAX 512  // community size cap (multinomial mean 384, sigma 18 -> +7 sigma)
#define SCP 516    // sc row stride (516*4B = 2064B, 16B-aligned)
#define KS 16      // key splits: 768 blocks = 3/CU exactly
#define NW 17      // weight matrices (16x 256x256 + 1x 256x512)

typedef __attribute__((ext_vector_type(8))) short short8;
typedef __attribute__((ext_vector_type(4))) short short4v;
typedef __attribute__((ext_vector_type(4))) float f32x4;

__device__ __forceinline__ short f2bf_s(float f){
    __hip_bfloat16 h = __float2bfloat16(f);
    return *reinterpret_cast<short*>(&h);
}
__device__ __forceinline__ float bf2f_s(short v){
    __hip_bfloat16 h;
    *reinterpret_cast<short*>(&h) = v;
    return __bfloat162float(h);
}

// ---------------- batched weight transpose+cast (+ fused embedding at z==NW) ----------------
// r9: k_embed folded in as the z==NW slice (128 blocks grid-stride over NN*DD).
// Same math, -1 dispatch.
struct WT {
    const float* src[NW];
    short*       dst[NW];
    int          M[NW];
    const float* x; const float* emb_w; const float* emb_b; const float* pos;
    float* h; short* hbf; short* hpbf;
};
__global__ __launch_bounds__(256) void k_wtrans(WT wt){
    int id = blockIdx.z;
    if (id == NW){
        int t = (blockIdx.y * 16 + blockIdx.x) * 256 + threadIdx.x;  // 0..32767
        for (int i = t; i < NN * DD; i += 16 * 8 * 256){
            int n = i >> 8, d = i & 255;
            float v = wt.x[n] * wt.emb_w[d] + wt.emb_b[d];
            wt.h[i] = v;
            wt.hbf[i] = f2bf_s(v);
            wt.hpbf[i] = f2bf_s(v + wt.pos[i]);
        }
        return;
    }
    int M = wt.M[id];
    int bx = blockIdx.x;
    if (bx * 32 >= M) return;
    int by = blockIdx.y;
    __shared__ float t[32][33];
    int lx = threadIdx.x & 31, ly = threadIdx.x >> 5;
    const float* w = wt.src[id];
    for (int i = ly; i < 32; i += 8)
        t[i][lx] = w[(size_t)(by * 32 + i) * M + bx * 32 + lx];
    __syncthreads();
    short* d = wt.dst[id];
    for (int r = ly; r < 32; r += 8)
        d[(size_t)(bx * 32 + r) * DD + by * 32 + lx] = f2bf_s(t[lx][r]);
}

// ---------------- CSR build + community sort (fused, r9) ----------------
__global__ void k_count2(const int* __restrict__ ei, const int* __restrict__ comm,
                         int* __restrict__ cnt, int* __restrict__ ccnt){
    int e = blockIdx.x * 256 + threadIdx.x;
    if (e < EE) atomicAdd(&cnt[ei[e]], 1);
    if (e < NN) atomicAdd(&ccnt[comm[e]], 1);
}

__global__ void k_scan2(const int* __restrict__ cnt, int* __restrict__ rp,
                        const int* __restrict__ ccnt, int* __restrict__ cstart){
    __shared__ int part[256];
    int tid = threadIdx.x;
    int base = tid * 12;
    int loc[12]; int s = 0;
    for (int i = 0; i < 12; i++){ loc[i] = s; s += cnt[base + i]; }
    part[tid] = s; __syncthreads();
    if (tid == 0){ int a = 0; for (int i = 0; i < 256; i++){ int t = part[i]; part[i] = a; a += t; } }
    __syncthreads();
    int b = part[tid];
    for (int i = 0; i < 12; i++) rp[base + i] = b + loc[i];
    if (tid == 255) rp[NN] = b + s;
    if (tid == 0){
        cstart[0] = 0;
        for (int c = 0; c < NC; c++) cstart[c + 1] = cstart[c] + ccnt[c];
    }
}

__global__ void k_fill2(const int* __restrict__ ei, const int* __restrict__ et,
                        const int* __restrict__ rp, int* __restrict__ cur,
                        int* __restrict__ e_dst, int* __restrict__ e_typ,
                        const int* __restrict__ comm, const int* __restrict__ cstart,
                        int* __restrict__ ccur, int* __restrict__ perm, int* __restrict__ inv){
    int e = blockIdx.x * 256 + threadIdx.x;
    if (e < EE){
        int s = ei[e], d = ei[EE + e];
        int p = atomicAdd(&cur[s], 1);
        int idx = rp[s] + p;
        e_dst[idx] = d; e_typ[idx] = et[e];
    }
    if (e < NN){
        int c = comm[e];
        int p = cstart[c] + atomicAdd(&ccur[c], 1);
        perm[p] = e; inv[e] = p;
    }
}

// ---------------- MFMA GEMM (bf16 A): C[m][n] = A @ W + bias ----------------
template<int M>
__global__ __launch_bounds__(256) void k_gemm_mfma(
        const short* __restrict__ A, const short* __restrict__ Wt,
        const float* __restrict__ bias, float* __restrict__ C){
    int tid = threadIdx.x;
    int w = tid >> 6, lane = tid & 63, quad = lane >> 4, col = lane & 15;
    int m0 = blockIdx.x * 64 + w * 16;
    int n0 = blockIdx.y * 64;

    const short* arow = A + (size_t)(m0 + col) * DD;

    f32x4 acc[4];
    #pragma unroll
    for (int su = 0; su < 4; su++) acc[su] = (f32x4){0.f, 0.f, 0.f, 0.f};

    #pragma unroll
    for (int f = 0; f < 8; f++){
        int k0 = f * 32 + quad * 8;
        short8 af = *(const short8*)(arow + k0);
        #pragma unroll
        for (int su = 0; su < 4; su++){
            short8 bf = *(const short8*)(Wt + (size_t)(n0 + su * 16 + col) * DD + k0);
            acc[su] = __builtin_amdgcn_mfma_f32_16x16x32_bf16(af, bf, acc[su], 0, 0, 0);
        }
    }

    #pragma unroll
    for (int su = 0; su < 4; su++){
        int n = n0 + su * 16 + col;
        float bz = bias[n];
        #pragma unroll
        for (int r = 0; r < 4; r++)
            C[(size_t)(m0 + quad * 4 + r) * M + n] = acc[su][r] + bz;
    }
}

// ---------------- fused QKV MFMA GEMM (bf16 A) ----------------
// r4/r5: V-transpose fused. z==2 writes V^T[n][m] directly as packed short4.
// For local layers A-rows are gathered via perm so m IS the sorted position.
struct QKV {
    const short* Wt[3];
    const float* bias[3];
    short*       Cb[2];    // Q, K row-major bf16 outs
    short*       VtOut;    // V^T [DD][NN] bf16
};
__global__ __launch_bounds__(256) void k_gemm_qkv(
        const short* __restrict__ A, QKV q, const int* __restrict__ permRow){
    int z = blockIdx.z;
    const short* Wt = q.Wt[z];
    const float* bias = q.bias[z];

    int tid = threadIdx.x;
    int w = tid >> 6, lane = tid & 63, quad = lane >> 4, col = lane & 15;
    int m0 = blockIdx.x * 64 + w * 16;
    int n0 = blockIdx.y * 64;

    int arowIdx = m0 + col;
    if (permRow) arowIdx = permRow[arowIdx];
    const short* arow = A + (size_t)arowIdx * DD;

    f32x4 acc[4];
    #pragma unroll
    for (int su = 0; su < 4; su++) acc[su] = (f32x4){0.f, 0.f, 0.f, 0.f};

    #pragma unroll
    for (int f = 0; f < 8; f++){
        int k0 = f * 32 + quad * 8;
        short8 af = *(const short8*)(arow + k0);
        #pragma unroll
        for (int su = 0; su < 4; su++){
            short8 bf = *(const short8*)(Wt + (size_t)(n0 + su * 16 + col) * DD + k0);
            acc[su] = __builtin_amdgcn_mfma_f32_16x16x32_bf16(af, bf, acc[su], 0, 0, 0);
        }
    }

    if (z == 2){
        // V^T: for fixed n, the 4 r-values are m-consecutive -> packed short4
        #pragma unroll
        for (int su = 0; su < 4; su++){
            int n = n0 + su * 16 + col;
            float bz = bias[n];
            short4v pk;
            #pragma unroll
            for (int r = 0; r < 4; r++) pk[r] = f2bf_s(acc[su][r] + bz);
            *(short4v*)(q.VtOut + (size_t)n * NN + m0 + quad * 4) = pk;
        }
    } else {
        short* Cb = q.Cb[z];
        #pragma unroll
        for (int su = 0; su < 4; su++){
            int n = n0 + su * 16 + col;
            float bz = bias[n];
            #pragma unroll
            for (int r = 0; r < 4; r++)
                Cb[(size_t)(m0 + quad * 4 + r) * DD + n] = f2bf_s(acc[su][r] + bz);
        }
    }
}

// ---------------- fused O-proj GEMM + residual + LayerNorm ----------------
// r6: template<MERGE>. MERGE=1 (global layers) fuses the old k_gmerge.
template<int MERGE>
__global__ __launch_bounds__(256) void k_gemm_o_ln(
        const short* __restrict__ A,
        const short* __restrict__ Opart, const float* __restrict__ lpart,
        const short* __restrict__ Wt, const float* __restrict__ bias,
        const float* __restrict__ g, const float* __restrict__ b,
        const float* __restrict__ pos,
        float* __restrict__ h, short* __restrict__ hbf, short* __restrict__ hpbf){
    __shared__ float t[16][258];                 // 16.5 KB
    __shared__ short Al[MERGE ? 16 * 256 : 1];   // 8 KB (MERGE only)
    __shared__ float lsum[MERGE ? 16 : 1];
    int tid = threadIdx.x;
    int w = tid >> 6, lane = tid & 63, quad = lane >> 4, col = lane & 15;
    int m0 = blockIdx.x * 16;
    int n0 = w * 64;

    const short* arow = A ? A + (size_t)(m0 + col) * DD : nullptr;

    if (MERGE){
        if (tid < 16){
            float l = 0.f;
            for (int s = 0; s < KS; s++) l += lpart[s * NN + m0 + tid];
            lsum[tid] = l;
        }
        __syncthreads();
        #pragma unroll
        for (int i = 0; i < 2; i++){
            int c = tid + i * 256;               // 512 chunks of short8
            int row = c >> 5, seg = c & 31;
            const short* src = Opart + (size_t)(m0 + row) * DD + seg * 8;
            float v[8] = {0.f,0.f,0.f,0.f,0.f,0.f,0.f,0.f};
            for (int s = 0; s < KS; s++){
                short8 o = *(const short8*)(src + (size_t)s * NN * DD);
                #pragma unroll
                for (int j = 0; j < 8; j++) v[j] += bf2f_s(o[j]);
            }
            float lr = lsum[row];
            short8 res;
            #pragma unroll
            for (int j = 0; j < 8; j++) res[j] = f2bf_s(v[j] / lr);
            *(short8*)&Al[(row << 8) + ((seg * 8) ^ ((row & 7) << 3))] = res;
        }
        __syncthreads();
    }

    f32x4 acc[4];
    #pragma unroll
    for (int su = 0; su < 4; su++) acc[su] = (f32x4){0.f, 0.f, 0.f, 0.f};

    #pragma unroll
    for (int f = 0; f < 8; f++){
        int k0 = f * 32 + quad * 8;
        short8 af;
        if (MERGE) af = *(const short8*)&Al[(col << 8) + (k0 ^ ((col & 7) << 3))];
        else       af = *(const short8*)(arow + k0);
        #pragma unroll
        for (int su = 0; su < 4; su++){
            short8 bf = *(const short8*)(Wt + (size_t)(n0 + su * 16 + col) * DD + k0);
            acc[su] = __builtin_amdgcn_mfma_f32_16x16x32_bf16(af, bf, acc[su], 0, 0, 0);
        }
    }

    #pragma unroll
    for (int su = 0; su < 4; su++){
        int n = n0 + su * 16 + col;
        float bz = bias[n];
        #pragma unroll
        for (int r = 0; r < 4; r++)
            t[quad * 4 + r][n] = acc[su][r] + bz;
    }
    __syncthreads();

    // ---- residual + LN: row = tid>>4, 16 lanes per row, 16 d's per lane
    int row = tid >> 4, l16 = tid & 15;
    int m = m0 + row;
    float v[16];
    float s = 0.f;
    #pragma unroll
    for (int j = 0; j < 16; j++){
        int d = l16 + j * 16;
        float vv = t[row][d] + h[(size_t)m * DD + d];
        v[j] = vv; s += vv;
    }
    #pragma unroll
    for (int off = 1; off < 16; off <<= 1) s += __shfl_xor(s, off);
    float mean = s * (1.0f / 256.0f);
    float s2 = 0.f;
    #pragma unroll
    for (int j = 0; j < 16; j++){ float c = v[j] - mean; s2 += c * c; }
    #pragma unroll
    for (int off = 1; off < 16; off <<= 1) s2 += __shfl_xor(s2, off);
    float rstd = rsqrtf(s2 * (1.0f / 256.0f) + 1e-5f);
    #pragma unroll
    for (int j = 0; j < 16; j++){
        int d = l16 + j * 16;
        float out = (v[j] - mean) * rstd * g[d] + b[d];
        size_t idx = (size_t)m * DD + d;
        h[idx] = out;
        hbf[idx] = f2bf_s(out);
        if (pos) hpbf[idx] = f2bf_s(out + pos[idx]);
    }
}

// ---------------- local attention v6: 33KB LDS -> 4 blocks/CU ----------------
__global__ __launch_bounds__(256) void k_local_attn6(
        const short* __restrict__ Qs, const short* __restrict__ Ks, const short* __restrict__ Vts,
        const int* __restrict__ cstart, const int* __restrict__ perm, const int* __restrict__ inv,
        const int* __restrict__ rp, const int* __restrict__ e_dst, const int* __restrict__ e_typ,
        const float* __restrict__ eb, short* __restrict__ obbf){
    int c  = blockIdx.y;
    int hh = blockIdx.z;
    int cs0 = cstart[c], cs1 = cstart[c + 1];
    int Nc = cs1 - cs0;
    int p0 = blockIdx.x * 16;
    if (p0 >= Nc) return;
    int tid = threadIdx.x;
    int w = tid >> 6, lane = tid & 63, quad = lane >> 4, col = lane & 15;
    int nt  = (Nc + 15) >> 4;
    int nt2 = (Nc + 31) >> 5;

    __shared__ float sc[16][SCP];
    __shared__ float linv[16];
    __shared__ int qnode[16];

    if (tid < 16) qnode[tid] = (p0 + tid < Nc) ? perm[cs0 + p0 + tid] : -1;

    int qrow = cs0 + min(p0 + col, Nc - 1);
    short8 qf = *(const short8*)(Qs + (size_t)qrow * DD + hh * DHH + quad * 8);

    const float scale = 0.17677669529663687f; // 1/sqrt(32)

    for (int t = w; t < nt; t += 4){
        int kt = t * 16;
        int krow = cs0 + min(kt + col, Nc - 1);
        short8 kf = *(const short8*)(Ks + (size_t)krow * DD + hh * DHH + quad * 8);
        f32x4 s = __builtin_amdgcn_mfma_f32_16x16x32_bf16(qf, kf, (f32x4){0.f,0.f,0.f,0.f}, 0, 0, 0);
        #pragma unroll
        for (int r = 0; r < 4; r++)
            sc[quad * 4 + r][kt + col] = s[r] * scale;
    }
    __syncthreads();

    int qi = tid >> 4, l16 = tid & 15;
    {
        int n = qnode[qi];
        if (n >= 0){
            int re = rp[n + 1];
            for (int e2 = rp[n] + l16; e2 < re; e2 += 16){
                int dpos = inv[e_dst[e2]];
                if (dpos >= cs0 && dpos < cs1)
                    atomicAdd(&sc[qi][dpos - cs0], eb[e_typ[e2] * HH + hh]);
            }
        }
    }
    __syncthreads();

    {
        float lm = -1e30f;
        for (int m = l16; m < Nc; m += 16) lm = fmaxf(lm, sc[qi][m]);
        #pragma unroll
        for (int off = 1; off < 16; off <<= 1) lm = fmaxf(lm, __shfl_xor(lm, off));
        float ls = 0.f;
        for (int m = l16; m < Nc; m += 16){
            float e_ = __expf(sc[qi][m] - lm);
            sc[qi][m] = e_;
            ls += e_;
        }
        for (int m = (Nc & ~15) + l16; m < nt2 * 32; m += 16)
            if (m >= Nc) sc[qi][m] = 0.f;
        #pragma unroll
        for (int off = 1; off < 16; off <<= 1) ls += __shfl_xor(ls, off);
        if (l16 == 0) linv[qi] = 1.f / ls;
    }
    __syncthreads();

    f32x4 acc0 = (f32x4){0.f,0.f,0.f,0.f}, acc1 = (f32x4){0.f,0.f,0.f,0.f};
    for (int t2 = w; t2 < nt2; t2 += 4){
        int kt = t2 * 32;
        float4 pa = *(const float4*)&sc[col][kt + quad * 8];
        float4 pb = *(const float4*)&sc[col][kt + quad * 8 + 4];
        short8 pf;
        pf[0] = f2bf_s(pa.x); pf[1] = f2bf_s(pa.y); pf[2] = f2bf_s(pa.z); pf[3] = f2bf_s(pa.w);
        pf[4] = f2bf_s(pb.x); pf[5] = f2bf_s(pb.y); pf[6] = f2bf_s(pb.z); pf[7] = f2bf_s(pb.w);
        const short* vb0 = Vts + (size_t)(hh * DHH + col) * NN + cs0 + kt + quad * 8;
        short8 vf0 = *(const short8*)(vb0);
        short8 vf1 = *(const short8*)(vb0 + (size_t)16 * NN);
        acc0 = __builtin_amdgcn_mfma_f32_16x16x32_bf16(pf, vf0, acc0, 0, 0, 0);
        acc1 = __builtin_amdgcn_mfma_f32_16x16x32_bf16(pf, vf1, acc1, 0, 0, 0);
    }
    __syncthreads();   // all waves done READING sc -> safe to alias as pv
    {
        float (*pv)[16][33] = reinterpret_cast<float (*)[16][33]>(&sc[0][0]); // 8.45KB < 33KB
        #pragma unroll
        for (int r = 0; r < 4; r++){
            pv[w][quad * 4 + r][col]      = acc0[r];
            pv[w][quad * 4 + r][col + 16] = acc1[r];
        }
        __syncthreads();

        int q = tid >> 4, d0 = tid & 15;
        int n = qnode[q];
        #pragma unroll
        for (int half = 0; half < 2; half++){
            int dd = d0 + half * 16;
            float sum = pv[0][q][dd] + pv[1][q][dd] + pv[2][q][dd] + pv[3][q][dd];
            if (n >= 0) obbf[(size_t)n * DD + hh * DHH + dd] = f2bf_s(sum * linv[q]);
        }
    }
}

// ---------------- global attention v10+ (r8-proven, unchanged) ----------------
__global__ __launch_bounds__(256) void k_glob_mfma10(
        const short* __restrict__ Qb, const short* __restrict__ Kb,
        const short* __restrict__ Vt, const int* __restrict__ comm,
        short* __restrict__ Opart, float* __restrict__ lpart){
    int tid = threadIdx.x;
    int w = tid >> 6, lane = tid & 63, quad = lane >> 4, col = lane & 15;
    int qt = blockIdx.x * 64 + w * 16;
    int split = blockIdx.y;
    int ks0 = split * (NN / KS);   // 192 keys/split
    const int NT = NN / KS / 32;   // 6 key tiles

    __shared__ __align__(16) short Kl[32 * 256];  // 16.0 KB, XOR-swizzled
    __shared__ __align__(16) short Vl[256][40];   // 20.5 KB, V^T tile [d][key]
    __shared__ __align__(16) short Pl[4][16][40]; // 5.1 KB, per-wave P tiles

    short8 qf[8];
    #pragma unroll
    for (int f = 0; f < 8; f++)
        qf[f] = *(const short8*)(Qb + (size_t)(qt + col) * DD + f * 32 + quad * 8);

    int qc[4];
    #pragma unroll
    for (int r = 0; r < 4; r++) qc[r] = comm[qt + quad * 4 + r];

    f32x4 accO[16];
    #pragma unroll
    for (int dt = 0; dt < 16; dt++) accO[dt] = (f32x4){0.f, 0.f, 0.f, 0.f};
    float l_[4] = {0.f, 0.f, 0.f, 0.f};

    const float scale = 0.17677669529663687f; // 1/sqrt(32) per reference

    // per-thread staging geometry (chunk idx = tid + i*256)
    int ksg = tid & 31;            // K: 16B chunk within row
    int kr0 = tid >> 5;            // K: base row (+8 per i) -> (row&7) const per thread
    int ksw = (kr0 & 7) << 3;      // swizzle XOR, in shorts
    int vsg = tid & 3;             // V: chunk within d-row
    int vd0 = tid >> 2;            // V: base d (+64 per i)

    short8 kpre[4], vpre[4];
    #pragma unroll
    for (int i = 0; i < 4; i++){
        kpre[i] = *(const short8*)(Kb + (size_t)(ks0 + kr0 + 8 * i) * DD + ksg * 8);
        vpre[i] = *(const short8*)(Vt + (size_t)(vd0 + 64 * i) * NN + ks0 + vsg * 8);
    }
    int cm0n = comm[ks0 + col];
    int cm1n = comm[ks0 + 16 + col];

    for (int t = 0; t < NT; t++){
        int kt = ks0 + t * 32;
        __syncthreads();           // prev iteration's LDS reads complete
        #pragma unroll
        for (int i = 0; i < 4; i++){
            *(short8*)&Kl[(kr0 + 8 * i) * 256 + ((ksg * 8) ^ ksw)] = kpre[i];
            *(short8*)&Vl[vd0 + 64 * i][vsg * 8] = vpre[i];
        }
        __syncthreads();
        int cm0 = cm0n, cm1 = cm1n;
        if (t + 1 < NT){           // prefetch next tile; hides under MFMA below
            int kn = kt + 32;
            #pragma unroll
            for (int i = 0; i < 4; i++){
                kpre[i] = *(const short8*)(Kb + (size_t)(kn + kr0 + 8 * i) * DD + ksg * 8);
                vpre[i] = *(const short8*)(Vt + (size_t)(vd0 + 64 * i) * NN + kn + vsg * 8);
            }
            cm0n = comm[kn + col];
            cm1n = comm[kn + 16 + col];
        }

        // ---- S: 16 q x 32 keys from swizzled LDS frags
        f32x4 s0 = (f32x4){0.f,0.f,0.f,0.f}, s1 = (f32x4){0.f,0.f,0.f,0.f};
        int csw = (col & 7) << 3;  // (16+col)&7 == col&7
        #pragma unroll
        for (int f = 0; f < 8; f++){
            int cs = (f * 32 + quad * 8) ^ csw;
            short8 kf0 = *(const short8*)&Kl[col * 256 + cs];
            short8 kf1 = *(const short8*)&Kl[(16 + col) * 256 + cs];
            s0 = __builtin_amdgcn_mfma_f32_16x16x32_bf16(qf[f], kf0, s0, 0, 0, 0);
            s1 = __builtin_amdgcn_mfma_f32_16x16x32_bf16(qf[f], kf1, s1, 0, 0, 0);
        }

        #pragma unroll
        for (int r = 0; r < 4; r++){
            float p0 = (cm0 != qc[r]) ? __expf(s0[r] * scale) : 0.f;
            float p1 = (cm1 != qc[r]) ? __expf(s1[r] * scale) : 0.f;
            l_[r] += p0 + p1;
            int row = quad * 4 + r;
            Pl[w][row][col]      = f2bf_s(p0);
            Pl[w][row][col + 16] = f2bf_s(p1);
        }
        short8 pf = *(const short8*)(&Pl[w][col][quad * 8]);
        // ---- PV: V frags from LDS
        #pragma unroll
        for (int dt = 0; dt < 16; dt++){
            short8 vf = *(const short8*)&Vl[dt * 16 + col][quad * 8];
            accO[dt] = __builtin_amdgcn_mfma_f32_16x16x32_bf16(pf, vf, accO[dt], 0, 0, 0);
        }
    }

    #pragma unroll
    for (int r = 0; r < 4; r++){
        float vv = l_[r];
        #pragma unroll
        for (int off = 1; off < 16; off <<= 1) vv += __shfl_xor(vv, off);
        l_[r] = vv;
    }

    #pragma unroll
    for (int r = 0; r < 4; r++){
        int row = qt + quad * 4 + r;
        if (col == 0) lpart[split * NN + row] = l_[r];
        #pragma unroll
        for (int dt = 0; dt < 16; dt++)
            Opart[((size_t)split * NN + row) * DD + dt * 16 + col] = f2bf_s(accO[dt][r]);
    }
}

// ---------------- host ----------------
extern "C" void kernel_launch(void* const* d_in, const int* in_sizes, int n_in,
                              void* d_out, int out_size, void* d_ws, size_t ws_size,
                              hipStream_t stream){
    const float* x        = (const float*)d_in[0];
    const int*   ei       = (const int*)  d_in[1];
    const int*   et       = (const int*)  d_in[2];
    const float* pos      = (const float*)d_in[3];
    const int*   comm     = (const int*)  d_in[4];
    const float* emb_w    = (const float*)d_in[6];
    const float* emb_b    = (const float*)d_in[7];
    const float* loc_qw   = (const float*)d_in[8];
    const float* loc_qb   = (const float*)d_in[9];
    const float* loc_kw   = (const float*)d_in[10];
    const float* loc_kb   = (const float*)d_in[11];
    const float* loc_vw   = (const float*)d_in[12];
    const float* loc_vb   = (const float*)d_in[13];
    const float* loc_ow   = (const float*)d_in[14];
    const float* loc_ob   = (const float*)d_in[15];
    const float* loc_eb   = (const float*)d_in[16];
    const float* loc_ln_g = (const float*)d_in[17];
    const float* loc_ln_b = (const float*)d_in[18];
    const float* glob_qw  = (const float*)d_in[19];
    const float* glob_qb  = (const float*)d_in[20];
    const float* glob_kw  = (const float*)d_in[21];
    const float* glob_kb  = (const float*)d_in[22];
    const float* glob_vw  = (const float*)d_in[23];
    const float* glob_vb  = (const float*)d_in[24];
    const float* glob_ow  = (const float*)d_in[25];
    const float* glob_ob  = (const float*)d_in[26];
    const float* glob_ln_g= (const float*)d_in[27];
    const float* glob_ln_b= (const float*)d_in[28];
    const float* out_w    = (const float*)d_in[29];
    const float* out_b    = (const float*)d_in[30];

    float* h    = (float*)d_ws;           // NN*DD f32
    float* lpart= h + NN * DD;            // KS*NN
    int* cnt    = (int*)(lpart + KS * NN);
    int* cur    = cnt + NN;
    int* ccnt   = cur + NN;
    int* ccur   = ccnt + NC;
    int* cstart = ccur + NC;
    int* rp     = cstart + NC + 1;
    int* perm   = rp + NN + 1;
    int* inv    = perm + NN;
    int* e_dst  = inv + NN;
    int* e_typ  = e_dst + EE;
    short* Qbf  = (short*)(((uintptr_t)(e_typ + EE) + 15) & ~(uintptr_t)15);
    short* Kbf  = Qbf + NN * DD;
    short* Vt   = Kbf + NN * DD;          // [DD][NN]
    short* WtAll= Vt + (size_t)DD * NN;   // 16*65536 + 131072 shorts
    short* Qs   = WtAll + 16 * DD * DD + DD * OO;  // sorted bf16 Q [NN][DD]
    short* Ks2  = Qs + (size_t)NN * DD;            // sorted bf16 K
    short* Vts  = Ks2 + (size_t)NN * DD;           // sorted V^T [DD][NN]
    short* Opart= Vts + (size_t)DD * NN;           // KS*NN*DD bf16
    short* hbf  = Opart + (size_t)KS * NN * DD;    // bf16(h)
    short* hpbf = hbf + (size_t)NN * DD;           // bf16(h+pos)
    short* obbf = hpbf + (size_t)NN * DD;          // bf16 attn output (local GEMM A)

    WT wt;
    const float* wsrc[NW] = {
        loc_qw, loc_kw, loc_vw, loc_ow,
        loc_qw + DD * DD, loc_kw + DD * DD, loc_vw + DD * DD, loc_ow + DD * DD,
        glob_qw, glob_kw, glob_vw, glob_ow,
        glob_qw + DD * DD, glob_kw + DD * DD, glob_vw + DD * DD, glob_ow + DD * DD,
        out_w };
    for (int i = 0; i < NW; i++){
        wt.src[i] = wsrc[i];
        wt.dst[i] = WtAll + (size_t)i * DD * DD;
        wt.M[i]   = (i == 16) ? OO : DD;
    }
    wt.x = x; wt.emb_w = emb_w; wt.emb_b = emb_b; wt.pos = pos;
    wt.h = h; wt.hbf = hbf; wt.hpbf = hpbf;
    short* WtLQ[2] = { WtAll + 0 * DD * DD, WtAll + 4 * DD * DD };
    short* WtLK[2] = { WtAll + 1 * DD * DD, WtAll + 5 * DD * DD };
    short* WtLV[2] = { WtAll + 2 * DD * DD, WtAll + 6 * DD * DD };
    short* WtLO[2] = { WtAll + 3 * DD * DD, WtAll + 7 * DD * DD };
    short* WtGQ[2] = { WtAll + 8 * DD * DD, WtAll + 12 * DD * DD };
    short* WtGK[2] = { WtAll + 9 * DD * DD, WtAll + 13 * DD * DD };
    short* WtGV[2] = { WtAll + 10 * DD * DD, WtAll + 14 * DD * DD };
    short* WtGO[2] = { WtAll + 11 * DD * DD, WtAll + 15 * DD * DD };
    short* WtOut   = WtAll + 16 * DD * DD;

    (void)hipMemsetAsync(cnt, 0, sizeof(int) * (2 * NN + 2 * NC), stream);

    k_wtrans<<<dim3(16, 8, NW + 1), 256, 0, stream>>>(wt);
    k_count2<<<EE / 256, 256, 0, stream>>>(ei, comm, cnt, ccnt);
    k_scan2<<<1, 256, 0, stream>>>(cnt, rp, ccnt, cstart);
    k_fill2<<<EE / 256, 256, 0, stream>>>(ei, et, rp, cur, e_dst, e_typ,
                                          comm, cstart, ccur, perm, inv);

    for (int l = 0; l < 2; l++){
        QKV q;
        q.Wt[0] = WtLQ[l]; q.Wt[1] = WtLK[l]; q.Wt[2] = WtLV[l];
        q.bias[0] = loc_qb + l * DD; q.bias[1] = loc_kb + l * DD; q.bias[2] = loc_vb + l * DD;
        q.Cb[0] = Qs; q.Cb[1] = Ks2;
        q.VtOut = Vts;
        // A-rows permuted -> outputs land directly in sorted space
        k_gemm_qkv<<<dim3(NN / 64, DD / 64, 3), 256, 0, stream>>>(hpbf, q, perm);
        k_local_attn6<<<dim3(NCMAX / 16, NC, HH), 256, 0, stream>>>(
            Qs, Ks2, Vts, cstart, perm, inv, rp, e_dst, e_typ,
            loc_eb + l * NETT * HH, obbf);
        k_gemm_o_ln<0><<<NN / 16, 256, 0, stream>>>(
            obbf, nullptr, nullptr,
            WtLO[l], loc_ob + l * DD, loc_ln_g + l * DD, loc_ln_b + l * DD,
            (l == 0) ? pos : nullptr, h, hbf, hpbf);
    }

    for (int g = 0; g < 2; g++){
        QKV q;
        q.Wt[0] = WtGQ[g]; q.Wt[1] = WtGK[g]; q.Wt[2] = WtGV[g];
        q.bias[0] = glob_qb + g * DD; q.bias[1] = glob_kb + g * DD; q.bias[2] = glob_vb + g * DD;
        q.Cb[0] = Qbf; q.Cb[1] = Kbf;
        q.VtOut = Vt;
        k_gemm_qkv<<<dim3(NN / 64, DD / 64, 3), 256, 0, stream>>>(hbf, q, nullptr);
        k_glob_mfma10<<<dim3(NN / 64, KS), 256, 0, stream>>>(Qbf, Kbf, Vt, comm, Opart, lpart);
        k_gemm_o_ln<1><<<NN / 16, 256, 0, stream>>>(
            nullptr, Opart, lpart,
            WtGO[g], glob_ob + g * DD, glob_ln_g + g * DD, glob_ln_b + g * DD,
            nullptr, h, hbf, nullptr);
    }

    k_gemm_mfma<OO><<<dim3(NN / 64, OO / 64), 256, 0, stream>>>(hbf, WtOut, out_b, (float*)d_out);
}

// Round 10
// 462.619 us; speedup vs baseline: 1.0127x; 1.0127x over previous
//
#include <hip/hip_runtime.h>
#include <hip/hip_bf16.h>
#include <stdint.h>

#define NN 3072
#define EE 49152
#define DD 256
#define OO 512
#define HH 8
#define DHH 32
#define NETT 5
#define NC 8
#define NCMAX 512  // community size cap (multinomial mean 384, sigma 18 -> +7 sigma)
#define SCP 516    // sc row stride (516*4B = 2064B, 16B-aligned)
#define KS 16      // key splits: 768 blocks = 3/CU exactly
#define NW 17      // weight matrices (16x 256x256 + 1x 256x512)

typedef __attribute__((ext_vector_type(8))) short short8;
typedef __attribute__((ext_vector_type(4))) short short4v;
typedef __attribute__((ext_vector_type(4))) float f32x4;

__device__ __forceinline__ short f2bf_s(float f){
    __hip_bfloat16 h = __float2bfloat16(f);
    return *reinterpret_cast<short*>(&h);
}
__device__ __forceinline__ float bf2f_s(short v){
    __hip_bfloat16 h;
    *reinterpret_cast<short*>(&h) = v;
    return __bfloat162float(h);
}

// ---------------- embedding (+ bf16 A-operand precompute) ----------------
// r10: restored as standalone 3072-block kernel. r9's fusion into wtrans gave
// it only 128 blocks x 24 grid-stride iters -> serialized tail (+~10us).
__global__ void k_embed(const float* __restrict__ x, const float* __restrict__ w,
                        const float* __restrict__ b, const float* __restrict__ pos,
                        float* __restrict__ h, short* __restrict__ hbf, short* __restrict__ hpbf){
    int i = blockIdx.x * 256 + threadIdx.x;
    int n = i >> 8, d = i & 255;
    float v = x[n] * w[d] + b[d];
    h[i] = v;
    hbf[i] = f2bf_s(v);
    hpbf[i] = f2bf_s(v + pos[i]);   // bf16(h+pos): identical to old in-GEMM f32 add+cast
}

// ---------------- batched weight transpose+cast ----------------
struct WT {
    const float* src[NW];
    short*       dst[NW];
    int          M[NW];
};
__global__ __launch_bounds__(256) void k_wtrans(WT wt){
    int id = blockIdx.z;
    int M = wt.M[id];
    int bx = blockIdx.x;
    if (bx * 32 >= M) return;
    int by = blockIdx.y;
    __shared__ float t[32][33];
    int lx = threadIdx.x & 31, ly = threadIdx.x >> 5;
    const float* w = wt.src[id];
    for (int i = ly; i < 32; i += 8)
        t[i][lx] = w[(size_t)(by * 32 + i) * M + bx * 32 + lx];
    __syncthreads();
    short* d = wt.dst[id];
    for (int r = ly; r < 32; r += 8)
        d[(size_t)(bx * 32 + r) * DD + by * 32 + lx] = f2bf_s(t[lx][r]);
}

// ---------------- CSR build ----------------
__global__ void k_count(const int* __restrict__ ei, int* __restrict__ cnt){
    int e = blockIdx.x * 256 + threadIdx.x;
    if (e < EE) atomicAdd(&cnt[ei[e]], 1);
}

__global__ void k_scan(const int* __restrict__ cnt, int* __restrict__ rp){
    __shared__ int part[256];
    int tid = threadIdx.x;
    int base = tid * 12;
    int loc[12]; int s = 0;
    for (int i = 0; i < 12; i++){ loc[i] = s; s += cnt[base + i]; }
    part[tid] = s; __syncthreads();
    if (tid == 0){ int a = 0; for (int i = 0; i < 256; i++){ int t = part[i]; part[i] = a; a += t; } }
    __syncthreads();
    int b = part[tid];
    for (int i = 0; i < 12; i++) rp[base + i] = b + loc[i];
    if (tid == 255) rp[NN] = b + s;
}

__global__ void k_fill(const int* __restrict__ ei, const int* __restrict__ et,
                       const int* __restrict__ rp, int* __restrict__ cur,
                       int* __restrict__ e_dst, int* __restrict__ e_typ){
    int e = blockIdx.x * 256 + threadIdx.x;
    if (e < EE){
        int s = ei[e], d = ei[EE + e];
        int p = atomicAdd(&cur[s], 1);
        int idx = rp[s] + p;
        e_dst[idx] = d; e_typ[idx] = et[e];
    }
}

// ---------------- community sort ----------------
__global__ void k_ccount(const int* __restrict__ comm, int* __restrict__ ccnt){
    int n = blockIdx.x * 256 + threadIdx.x;
    if (n < NN) atomicAdd(&ccnt[comm[n]], 1);
}

__global__ void k_cscan(const int* __restrict__ ccnt, int* __restrict__ cstart){
    cstart[0] = 0;
    for (int c = 0; c < NC; c++) cstart[c + 1] = cstart[c] + ccnt[c];
}

__global__ void k_cfill(const int* __restrict__ comm, const int* __restrict__ cstart,
                        int* __restrict__ ccur, int* __restrict__ perm, int* __restrict__ inv){
    int n = blockIdx.x * 256 + threadIdx.x;
    if (n < NN){
        int c = comm[n];
        int p = cstart[c] + atomicAdd(&ccur[c], 1);
        perm[p] = n; inv[n] = p;
    }
}

// ---------------- MFMA GEMM (bf16 A): C[m][n] = A @ W + bias ----------------
template<int M>
__global__ __launch_bounds__(256) void k_gemm_mfma(
        const short* __restrict__ A, const short* __restrict__ Wt,
        const float* __restrict__ bias, float* __restrict__ C){
    int tid = threadIdx.x;
    int w = tid >> 6, lane = tid & 63, quad = lane >> 4, col = lane & 15;
    int m0 = blockIdx.x * 64 + w * 16;
    int n0 = blockIdx.y * 64;

    const short* arow = A + (size_t)(m0 + col) * DD;

    f32x4 acc[4];
    #pragma unroll
    for (int su = 0; su < 4; su++) acc[su] = (f32x4){0.f, 0.f, 0.f, 0.f};

    #pragma unroll
    for (int f = 0; f < 8; f++){
        int k0 = f * 32 + quad * 8;
        short8 af = *(const short8*)(arow + k0);
        #pragma unroll
        for (int su = 0; su < 4; su++){
            short8 bf = *(const short8*)(Wt + (size_t)(n0 + su * 16 + col) * DD + k0);
            acc[su] = __builtin_amdgcn_mfma_f32_16x16x32_bf16(af, bf, acc[su], 0, 0, 0);
        }
    }

    #pragma unroll
    for (int su = 0; su < 4; su++){
        int n = n0 + su * 16 + col;
        float bz = bias[n];
        #pragma unroll
        for (int r = 0; r < 4; r++)
            C[(size_t)(m0 + quad * 4 + r) * M + n] = acc[su][r] + bz;
    }
}

// ---------------- fused QKV MFMA GEMM (bf16 A) ----------------
// r4/r5: V-transpose fused. z==2 writes V^T[n][m] directly as packed short4.
// For local layers A-rows are gathered via perm so m IS the sorted position.
struct QKV {
    const short* Wt[3];
    const float* bias[3];
    short*       Cb[2];    // Q, K row-major bf16 outs
    short*       VtOut;    // V^T [DD][NN] bf16
};
__global__ __launch_bounds__(256) void k_gemm_qkv(
        const short* __restrict__ A, QKV q, const int* __restrict__ permRow){
    int z = blockIdx.z;
    const short* Wt = q.Wt[z];
    const float* bias = q.bias[z];

    int tid = threadIdx.x;
    int w = tid >> 6, lane = tid & 63, quad = lane >> 4, col = lane & 15;
    int m0 = blockIdx.x * 64 + w * 16;
    int n0 = blockIdx.y * 64;

    int arowIdx = m0 + col;
    if (permRow) arowIdx = permRow[arowIdx];
    const short* arow = A + (size_t)arowIdx * DD;

    f32x4 acc[4];
    #pragma unroll
    for (int su = 0; su < 4; su++) acc[su] = (f32x4){0.f, 0.f, 0.f, 0.f};

    #pragma unroll
    for (int f = 0; f < 8; f++){
        int k0 = f * 32 + quad * 8;
        short8 af = *(const short8*)(arow + k0);
        #pragma unroll
        for (int su = 0; su < 4; su++){
            short8 bf = *(const short8*)(Wt + (size_t)(n0 + su * 16 + col) * DD + k0);
            acc[su] = __builtin_amdgcn_mfma_f32_16x16x32_bf16(af, bf, acc[su], 0, 0, 0);
        }
    }

    if (z == 2){
        // V^T: for fixed n, the 4 r-values are m-consecutive -> packed short4
        #pragma unroll
        for (int su = 0; su < 4; su++){
            int n = n0 + su * 16 + col;
            float bz = bias[n];
            short4v pk;
            #pragma unroll
            for (int r = 0; r < 4; r++) pk[r] = f2bf_s(acc[su][r] + bz);
            *(short4v*)(q.VtOut + (size_t)n * NN + m0 + quad * 4) = pk;
        }
    } else {
        short* Cb = q.Cb[z];
        #pragma unroll
        for (int su = 0; su < 4; su++){
            int n = n0 + su * 16 + col;
            float bz = bias[n];
            #pragma unroll
            for (int r = 0; r < 4; r++)
                Cb[(size_t)(m0 + quad * 4 + r) * DD + n] = f2bf_s(acc[su][r] + bz);
        }
    }
}

// ---------------- fused O-proj GEMM + residual + LayerNorm ----------------
// r6: template<MERGE>. MERGE=1 (global layers) fuses the old k_gmerge.
template<int MERGE>
__global__ __launch_bounds__(256) void k_gemm_o_ln(
        const short* __restrict__ A,
        const short* __restrict__ Opart, const float* __restrict__ lpart,
        const short* __restrict__ Wt, const float* __restrict__ bias,
        const float* __restrict__ g, const float* __restrict__ b,
        const float* __restrict__ pos,
        float* __restrict__ h, short* __restrict__ hbf, short* __restrict__ hpbf){
    __shared__ float t[16][258];                 // 16.5 KB
    __shared__ short Al[MERGE ? 16 * 256 : 1];   // 8 KB (MERGE only)
    __shared__ float lsum[MERGE ? 16 : 1];
    int tid = threadIdx.x;
    int w = tid >> 6, lane = tid & 63, quad = lane >> 4, col = lane & 15;
    int m0 = blockIdx.x * 16;
    int n0 = w * 64;

    const short* arow = A ? A + (size_t)(m0 + col) * DD : nullptr;

    if (MERGE){
        if (tid < 16){
            float l = 0.f;
            for (int s = 0; s < KS; s++) l += lpart[s * NN + m0 + tid];
            lsum[tid] = l;
        }
        __syncthreads();
        #pragma unroll
        for (int i = 0; i < 2; i++){
            int c = tid + i * 256;               // 512 chunks of short8
            int row = c >> 5, seg = c & 31;
            const short* src = Opart + (size_t)(m0 + row) * DD + seg * 8;
            float v[8] = {0.f,0.f,0.f,0.f,0.f,0.f,0.f,0.f};
            for (int s = 0; s < KS; s++){
                short8 o = *(const short8*)(src + (size_t)s * NN * DD);
                #pragma unroll
                for (int j = 0; j < 8; j++) v[j] += bf2f_s(o[j]);
            }
            float lr = lsum[row];
            short8 res;
            #pragma unroll
            for (int j = 0; j < 8; j++) res[j] = f2bf_s(v[j] / lr);
            *(short8*)&Al[(row << 8) + ((seg * 8) ^ ((row & 7) << 3))] = res;
        }
        __syncthreads();
    }

    f32x4 acc[4];
    #pragma unroll
    for (int su = 0; su < 4; su++) acc[su] = (f32x4){0.f, 0.f, 0.f, 0.f};

    #pragma unroll
    for (int f = 0; f < 8; f++){
        int k0 = f * 32 + quad * 8;
        short8 af;
        if (MERGE) af = *(const short8*)&Al[(col << 8) + (k0 ^ ((col & 7) << 3))];
        else       af = *(const short8*)(arow + k0);
        #pragma unroll
        for (int su = 0; su < 4; su++){
            short8 bf = *(const short8*)(Wt + (size_t)(n0 + su * 16 + col) * DD + k0);
            acc[su] = __builtin_amdgcn_mfma_f32_16x16x32_bf16(af, bf, acc[su], 0, 0, 0);
        }
    }

    #pragma unroll
    for (int su = 0; su < 4; su++){
        int n = n0 + su * 16 + col;
        float bz = bias[n];
        #pragma unroll
        for (int r = 0; r < 4; r++)
            t[quad * 4 + r][n] = acc[su][r] + bz;
    }
    __syncthreads();

    // ---- residual + LN: row = tid>>4, 16 lanes per row, 16 d's per lane
    int row = tid >> 4, l16 = tid & 15;
    int m = m0 + row;
    float v[16];
    float s = 0.f;
    #pragma unroll
    for (int j = 0; j < 16; j++){
        int d = l16 + j * 16;
        float vv = t[row][d] + h[(size_t)m * DD + d];
        v[j] = vv; s += vv;
    }
    #pragma unroll
    for (int off = 1; off < 16; off <<= 1) s += __shfl_xor(s, off);
    float mean = s * (1.0f / 256.0f);
    float s2 = 0.f;
    #pragma unroll
    for (int j = 0; j < 16; j++){ float c = v[j] - mean; s2 += c * c; }
    #pragma unroll
    for (int off = 1; off < 16; off <<= 1) s2 += __shfl_xor(s2, off);
    float rstd = rsqrtf(s2 * (1.0f / 256.0f) + 1e-5f);
    #pragma unroll
    for (int j = 0; j < 16; j++){
        int d = l16 + j * 16;
        float out = (v[j] - mean) * rstd * g[d] + b[d];
        size_t idx = (size_t)m * DD + d;
        h[idx] = out;
        hbf[idx] = f2bf_s(out);
        if (pos) hpbf[idx] = f2bf_s(out + pos[idx]);
    }
}

// ---------------- local attention v7: v6 + K/V global-load prefetch ----------------
// r10: QK-phase kf load (16 scattered 16B segs, ~500cy) issued one iteration
// ahead; PV-phase V loads prefetched one iteration ahead AND the first V tile
// issued BEFORE the softmax phase (address independent of softmax) -> first
// load hides under the whole bias+softmax section. +24 VGPR (88->~112, under
// the 128 cliff); LDS unchanged (33KB -> 4 blocks/CU). Math bit-identical.
__global__ __launch_bounds__(256) void k_local_attn7(
        const short* __restrict__ Qs, const short* __restrict__ Ks, const short* __restrict__ Vts,
        const int* __restrict__ cstart, const int* __restrict__ perm, const int* __restrict__ inv,
        const int* __restrict__ rp, const int* __restrict__ e_dst, const int* __restrict__ e_typ,
        const float* __restrict__ eb, short* __restrict__ obbf){
    int c  = blockIdx.y;
    int hh = blockIdx.z;
    int cs0 = cstart[c], cs1 = cstart[c + 1];
    int Nc = cs1 - cs0;
    int p0 = blockIdx.x * 16;
    if (p0 >= Nc) return;
    int tid = threadIdx.x;
    int w = tid >> 6, lane = tid & 63, quad = lane >> 4, col = lane & 15;
    int nt  = (Nc + 15) >> 4;
    int nt2 = (Nc + 31) >> 5;

    __shared__ float sc[16][SCP];
    __shared__ float linv[16];
    __shared__ int qnode[16];

    if (tid < 16) qnode[tid] = (p0 + tid < Nc) ? perm[cs0 + p0 + tid] : -1;

    int qrow = cs0 + min(p0 + col, Nc - 1);
    short8 qf = *(const short8*)(Qs + (size_t)qrow * DD + hh * DHH + quad * 8);

    const float scale = 0.17677669529663687f; // 1/sqrt(32)

    // ---- QK phase with 1-iteration K prefetch
    short8 kfn;
    if (w < nt){
        int krow = cs0 + min(w * 16 + col, Nc - 1);
        kfn = *(const short8*)(Ks + (size_t)krow * DD + hh * DHH + quad * 8);
    }
    for (int t = w; t < nt; t += 4){
        short8 kf = kfn;
        if (t + 4 < nt){
            int krow = cs0 + min((t + 4) * 16 + col, Nc - 1);
            kfn = *(const short8*)(Ks + (size_t)krow * DD + hh * DHH + quad * 8);
        }
        f32x4 s = __builtin_amdgcn_mfma_f32_16x16x32_bf16(qf, kf, (f32x4){0.f,0.f,0.f,0.f}, 0, 0, 0);
        int kt = t * 16;
        #pragma unroll
        for (int r = 0; r < 4; r++)
            sc[quad * 4 + r][kt + col] = s[r] * scale;
    }

    // ---- first PV V-tile prefetch (hides under bias scatter + softmax)
    short8 vf0n, vf1n;
    if (w < nt2){
        const short* vb0 = Vts + (size_t)(hh * DHH + col) * NN + cs0 + w * 32 + quad * 8;
        vf0n = *(const short8*)(vb0);
        vf1n = *(const short8*)(vb0 + (size_t)16 * NN);
    }
    __syncthreads();

    int qi = tid >> 4, l16 = tid & 15;
    {
        int n = qnode[qi];
        if (n >= 0){
            int re = rp[n + 1];
            for (int e2 = rp[n] + l16; e2 < re; e2 += 16){
                int dpos = inv[e_dst[e2]];
                if (dpos >= cs0 && dpos < cs1)
                    atomicAdd(&sc[qi][dpos - cs0], eb[e_typ[e2] * HH + hh]);
            }
        }
    }
    __syncthreads();

    {
        float lm = -1e30f;
        for (int m = l16; m < Nc; m += 16) lm = fmaxf(lm, sc[qi][m]);
        #pragma unroll
        for (int off = 1; off < 16; off <<= 1) lm = fmaxf(lm, __shfl_xor(lm, off));
        float ls = 0.f;
        for (int m = l16; m < Nc; m += 16){
            float e_ = __expf(sc[qi][m] - lm);
            sc[qi][m] = e_;
            ls += e_;
        }
        for (int m = (Nc & ~15) + l16; m < nt2 * 32; m += 16)
            if (m >= Nc) sc[qi][m] = 0.f;
        #pragma unroll
        for (int off = 1; off < 16; off <<= 1) ls += __shfl_xor(ls, off);
        if (l16 == 0) linv[qi] = 1.f / ls;
    }
    __syncthreads();

    f32x4 acc0 = (f32x4){0.f,0.f,0.f,0.f}, acc1 = (f32x4){0.f,0.f,0.f,0.f};
    for (int t2 = w; t2 < nt2; t2 += 4){
        int kt = t2 * 32;
        short8 vf0 = vf0n, vf1 = vf1n;
        if (t2 + 4 < nt2){
            const short* vbn = Vts + (size_t)(hh * DHH + col) * NN + cs0 + (t2 + 4) * 32 + quad * 8;
            vf0n = *(const short8*)(vbn);
            vf1n = *(const short8*)(vbn + (size_t)16 * NN);
        }
        float4 pa = *(const float4*)&sc[col][kt + quad * 8];
        float4 pb = *(const float4*)&sc[col][kt + quad * 8 + 4];
        short8 pf;
        pf[0] = f2bf_s(pa.x); pf[1] = f2bf_s(pa.y); pf[2] = f2bf_s(pa.z); pf[3] = f2bf_s(pa.w);
        pf[4] = f2bf_s(pb.x); pf[5] = f2bf_s(pb.y); pf[6] = f2bf_s(pb.z); pf[7] = f2bf_s(pb.w);
        acc0 = __builtin_amdgcn_mfma_f32_16x16x32_bf16(pf, vf0, acc0, 0, 0, 0);
        acc1 = __builtin_amdgcn_mfma_f32_16x16x32_bf16(pf, vf1, acc1, 0, 0, 0);
    }
    __syncthreads();   // all waves done READING sc -> safe to alias as pv
    {
        float (*pv)[16][33] = reinterpret_cast<float (*)[16][33]>(&sc[0][0]); // 8.45KB < 33KB
        #pragma unroll
        for (int r = 0; r < 4; r++){
            pv[w][quad * 4 + r][col]      = acc0[r];
            pv[w][quad * 4 + r][col + 16] = acc1[r];
        }
        __syncthreads();

        int q = tid >> 4, d0 = tid & 15;
        int n = qnode[q];
        #pragma unroll
        for (int half = 0; half < 2; half++){
            int dd = d0 + half * 16;
            float sum = pv[0][q][dd] + pv[1][q][dd] + pv[2][q][dd] + pv[3][q][dd];
            if (n >= 0) obbf[(size_t)n * DD + hh * DHH + dd] = f2bf_s(sum * linv[q]);
        }
    }
}

// ---------------- global attention v10+ (r8-proven, unchanged) ----------------
__global__ __launch_bounds__(256) void k_glob_mfma10(
        const short* __restrict__ Qb, const short* __restrict__ Kb,
        const short* __restrict__ Vt, const int* __restrict__ comm,
        short* __restrict__ Opart, float* __restrict__ lpart){
    int tid = threadIdx.x;
    int w = tid >> 6, lane = tid & 63, quad = lane >> 4, col = lane & 15;
    int qt = blockIdx.x * 64 + w * 16;
    int split = blockIdx.y;
    int ks0 = split * (NN / KS);   // 192 keys/split
    const int NT = NN / KS / 32;   // 6 key tiles

    __shared__ __align__(16) short Kl[32 * 256];  // 16.0 KB, XOR-swizzled
    __shared__ __align__(16) short Vl[256][40];   // 20.5 KB, V^T tile [d][key]
    __shared__ __align__(16) short Pl[4][16][40]; // 5.1 KB, per-wave P tiles

    short8 qf[8];
    #pragma unroll
    for (int f = 0; f < 8; f++)
        qf[f] = *(const short8*)(Qb + (size_t)(qt + col) * DD + f * 32 + quad * 8);

    int qc[4];
    #pragma unroll
    for (int r = 0; r < 4; r++) qc[r] = comm[qt + quad * 4 + r];

    f32x4 accO[16];
    #pragma unroll
    for (int dt = 0; dt < 16; dt++) accO[dt] = (f32x4){0.f, 0.f, 0.f, 0.f};
    float l_[4] = {0.f, 0.f, 0.f, 0.f};

    const float scale = 0.17677669529663687f; // 1/sqrt(32) per reference

    // per-thread staging geometry (chunk idx = tid + i*256)
    int ksg = tid & 31;            // K: 16B chunk within row
    int kr0 = tid >> 5;            // K: base row (+8 per i) -> (row&7) const per thread
    int ksw = (kr0 & 7) << 3;      // swizzle XOR, in shorts
    int vsg = tid & 3;             // V: chunk within d-row
    int vd0 = tid >> 2;            // V: base d (+64 per i)

    short8 kpre[4], vpre[4];
    #pragma unroll
    for (int i = 0; i < 4; i++){
        kpre[i] = *(const short8*)(Kb + (size_t)(ks0 + kr0 + 8 * i) * DD + ksg * 8);
        vpre[i] = *(const short8*)(Vt + (size_t)(vd0 + 64 * i) * NN + ks0 + vsg * 8);
    }
    int cm0n = comm[ks0 + col];
    int cm1n = comm[ks0 + 16 + col];

    for (int t = 0; t < NT; t++){
        int kt = ks0 + t * 32;
        __syncthreads();           // prev iteration's LDS reads complete
        #pragma unroll
        for (int i = 0; i < 4; i++){
            *(short8*)&Kl[(kr0 + 8 * i) * 256 + ((ksg * 8) ^ ksw)] = kpre[i];
            *(short8*)&Vl[vd0 + 64 * i][vsg * 8] = vpre[i];
        }
        __syncthreads();
        int cm0 = cm0n, cm1 = cm1n;
        if (t + 1 < NT){           // prefetch next tile; hides under MFMA below
            int kn = kt + 32;
            #pragma unroll
            for (int i = 0; i < 4; i++){
                kpre[i] = *(const short8*)(Kb + (size_t)(kn + kr0 + 8 * i) * DD + ksg * 8);
                vpre[i] = *(const short8*)(Vt + (size_t)(vd0 + 64 * i) * NN + kn + vsg * 8);
            }
            cm0n = comm[kn + col];
            cm1n = comm[kn + 16 + col];
        }

        // ---- S: 16 q x 32 keys from swizzled LDS frags
        f32x4 s0 = (f32x4){0.f,0.f,0.f,0.f}, s1 = (f32x4){0.f,0.f,0.f,0.f};
        int csw = (col & 7) << 3;  // (16+col)&7 == col&7
        #pragma unroll
        for (int f = 0; f < 8; f++){
            int cs = (f * 32 + quad * 8) ^ csw;
            short8 kf0 = *(const short8*)&Kl[col * 256 + cs];
            short8 kf1 = *(const short8*)&Kl[(16 + col) * 256 + cs];
            s0 = __builtin_amdgcn_mfma_f32_16x16x32_bf16(qf[f], kf0, s0, 0, 0, 0);
            s1 = __builtin_amdgcn_mfma_f32_16x16x32_bf16(qf[f], kf1, s1, 0, 0, 0);
        }

        #pragma unroll
        for (int r = 0; r < 4; r++){
            float p0 = (cm0 != qc[r]) ? __expf(s0[r] * scale) : 0.f;
            float p1 = (cm1 != qc[r]) ? __expf(s1[r] * scale) : 0.f;
            l_[r] += p0 + p1;
            int row = quad * 4 + r;
            Pl[w][row][col]      = f2bf_s(p0);
            Pl[w][row][col + 16] = f2bf_s(p1);
        }
        short8 pf = *(const short8*)(&Pl[w][col][quad * 8]);
        // ---- PV: V frags from LDS
        #pragma unroll
        for (int dt = 0; dt < 16; dt++){
            short8 vf = *(const short8*)&Vl[dt * 16 + col][quad * 8];
            accO[dt] = __builtin_amdgcn_mfma_f32_16x16x32_bf16(pf, vf, accO[dt], 0, 0, 0);
        }
    }

    #pragma unroll
    for (int r = 0; r < 4; r++){
        float vv = l_[r];
        #pragma unroll
        for (int off = 1; off < 16; off <<= 1) vv += __shfl_xor(vv, off);
        l_[r] = vv;
    }

    #pragma unroll
    for (int r = 0; r < 4; r++){
        int row = qt + quad * 4 + r;
        if (col == 0) lpart[split * NN + row] = l_[r];
        #pragma unroll
        for (int dt = 0; dt < 16; dt++)
            Opart[((size_t)split * NN + row) * DD + dt * 16 + col] = f2bf_s(accO[dt][r]);
    }
}

// ---------------- host ----------------
extern "C" void kernel_launch(void* const* d_in, const int* in_sizes, int n_in,
                              void* d_out, int out_size, void* d_ws, size_t ws_size,
                              hipStream_t stream){
    const float* x        = (const float*)d_in[0];
    const int*   ei       = (const int*)  d_in[1];
    const int*   et       = (const int*)  d_in[2];
    const float* pos      = (const float*)d_in[3];
    const int*   comm     = (const int*)  d_in[4];
    const float* emb_w    = (const float*)d_in[6];
    const float* emb_b    = (const float*)d_in[7];
    const float* loc_qw   = (const float*)d_in[8];
    const float* loc_qb   = (const float*)d_in[9];
    const float* loc_kw   = (const float*)d_in[10];
    const float* loc_kb   = (const float*)d_in[11];
    const float* loc_vw   = (const float*)d_in[12];
    const float* loc_vb   = (const float*)d_in[13];
    const float* loc_ow   = (const float*)d_in[14];
    const float* loc_ob   = (const float*)d_in[15];
    const float* loc_eb   = (const float*)d_in[16];
    const float* loc_ln_g = (const float*)d_in[17];
    const float* loc_ln_b = (const float*)d_in[18];
    const float* glob_qw  = (const float*)d_in[19];
    const float* glob_qb  = (const float*)d_in[20];
    const float* glob_kw  = (const float*)d_in[21];
    const float* glob_kb  = (const float*)d_in[22];
    const float* glob_vw  = (const float*)d_in[23];
    const float* glob_vb  = (const float*)d_in[24];
    const float* glob_ow  = (const float*)d_in[25];
    const float* glob_ob  = (const float*)d_in[26];
    const float* glob_ln_g= (const float*)d_in[27];
    const float* glob_ln_b= (const float*)d_in[28];
    const float* out_w    = (const float*)d_in[29];
    const float* out_b    = (const float*)d_in[30];

    float* h    = (float*)d_ws;           // NN*DD f32
    float* lpart= h + NN * DD;            // KS*NN
    int* cnt    = (int*)(lpart + KS * NN);
    int* cur    = cnt + NN;
    int* ccnt   = cur + NN;
    int* ccur   = ccnt + NC;
    int* cstart = ccur + NC;
    int* rp     = cstart + NC + 1;
    int* perm   = rp + NN + 1;
    int* inv    = perm + NN;
    int* e_dst  = inv + NN;
    int* e_typ  = e_dst + EE;
    short* Qbf  = (short*)(((uintptr_t)(e_typ + EE) + 15) & ~(uintptr_t)15);
    short* Kbf  = Qbf + NN * DD;
    short* Vt   = Kbf + NN * DD;          // [DD][NN]
    short* WtAll= Vt + (size_t)DD * NN;   // 16*65536 + 131072 shorts
    short* Qs   = WtAll + 16 * DD * DD + DD * OO;  // sorted bf16 Q [NN][DD]
    short* Ks2  = Qs + (size_t)NN * DD;            // sorted bf16 K
    short* Vts  = Ks2 + (size_t)NN * DD;           // sorted V^T [DD][NN]
    short* Opart= Vts + (size_t)DD * NN;           // KS*NN*DD bf16
    short* hbf  = Opart + (size_t)KS * NN * DD;    // bf16(h)
    short* hpbf = hbf + (size_t)NN * DD;           // bf16(h+pos)
    short* obbf = hpbf + (size_t)NN * DD;          // bf16 attn output (local GEMM A)

    WT wt;
    const float* wsrc[NW] = {
        loc_qw, loc_kw, loc_vw, loc_ow,
        loc_qw + DD * DD, loc_kw + DD * DD, loc_vw + DD * DD, loc_ow + DD * DD,
        glob_qw, glob_kw, glob_vw, glob_ow,
        glob_qw + DD * DD, glob_kw + DD * DD, glob_vw + DD * DD, glob_ow + DD * DD,
        out_w };
    for (int i = 0; i < NW; i++){
        wt.src[i] = wsrc[i];
        wt.dst[i] = WtAll + (size_t)i * DD * DD;
        wt.M[i]   = (i == 16) ? OO : DD;
    }
    short* WtLQ[2] = { WtAll + 0 * DD * DD, WtAll + 4 * DD * DD };
    short* WtLK[2] = { WtAll + 1 * DD * DD, WtAll + 5 * DD * DD };
    short* WtLV[2] = { WtAll + 2 * DD * DD, WtAll + 6 * DD * DD };
    short* WtLO[2] = { WtAll + 3 * DD * DD, WtAll + 7 * DD * DD };
    short* WtGQ[2] = { WtAll + 8 * DD * DD, WtAll + 12 * DD * DD };
    short* WtGK[2] = { WtAll + 9 * DD * DD, WtAll + 13 * DD * DD };
    short* WtGV[2] = { WtAll + 10 * DD * DD, WtAll + 14 * DD * DD };
    short* WtGO[2] = { WtAll + 11 * DD * DD, WtAll + 15 * DD * DD };
    short* WtOut   = WtAll + 16 * DD * DD;

    (void)hipMemsetAsync(cnt, 0, sizeof(int) * (2 * NN + 2 * NC), stream);

    k_embed<<<NN * DD / 256, 256, 0, stream>>>(x, emb_w, emb_b, pos, h, hbf, hpbf);
    k_wtrans<<<dim3(16, 8, NW), 256, 0, stream>>>(wt);
    k_count<<<EE / 256, 256, 0, stream>>>(ei, cnt);
    k_scan<<<1, 256, 0, stream>>>(cnt, rp);
    k_fill<<<EE / 256, 256, 0, stream>>>(ei, et, rp, cur, e_dst, e_typ);
    k_ccount<<<NN / 256, 256, 0, stream>>>(comm, ccnt);
    k_cscan<<<1, 1, 0, stream>>>(ccnt, cstart);
    k_cfill<<<NN / 256, 256, 0, stream>>>(comm, cstart, ccur, perm, inv);

    for (int l = 0; l < 2; l++){
        QKV q;
        q.Wt[0] = WtLQ[l]; q.Wt[1] = WtLK[l]; q.Wt[2] = WtLV[l];
        q.bias[0] = loc_qb + l * DD; q.bias[1] = loc_kb + l * DD; q.bias[2] = loc_vb + l * DD;
        q.Cb[0] = Qs; q.Cb[1] = Ks2;
        q.VtOut = Vts;
        // A-rows permuted -> outputs land directly in sorted space
        k_gemm_qkv<<<dim3(NN / 64, DD / 64, 3), 256, 0, stream>>>(hpbf, q, perm);
        k_local_attn7<<<dim3(NCMAX / 16, NC, HH), 256, 0, stream>>>(
            Qs, Ks2, Vts, cstart, perm, inv, rp, e_dst, e_typ,
            loc_eb + l * NETT * HH, obbf);
        k_gemm_o_ln<0><<<NN / 16, 256, 0, stream>>>(
            obbf, nullptr, nullptr,
            WtLO[l], loc_ob + l * DD, loc_ln_g + l * DD, loc_ln_b + l * DD,
            (l == 0) ? pos : nullptr, h, hbf, hpbf);
    }

    for (int g = 0; g < 2; g++){
        QKV q;
        q.Wt[0] = WtGQ[g]; q.Wt[1] = WtGK[g]; q.Wt[2] = WtGV[g];
        q.bias[0] = glob_qb + g * DD; q.bias[1] = glob_kb + g * DD; q.bias[2] = glob_vb + g * DD;
        q.Cb[0] = Qbf; q.Cb[1] = Kbf;
        q.VtOut = Vt;
        k_gemm_qkv<<<dim3(NN / 64, DD / 64, 3), 256, 0, stream>>>(hbf, q, nullptr);
        k_glob_mfma10<<<dim3(NN / 64, KS), 256, 0, stream>>>(Qbf, Kbf, Vt, comm, Opart, lpart);
        k_gemm_o_ln<1><<<NN / 16, 256, 0, stream>>>(
            nullptr, Opart, lpart,
            WtGO[g], glob_ob + g * DD, glob_ln_g + g * DD, glob_ln_b + g * DD,
            nullptr, h, hbf, nullptr);
    }

    k_gemm_mfma<OO><<<dim3(NN / 64, OO / 64), 256, 0, stream>>>(hbf, WtOut, out_b, (float*)d_out);
}

// Round 12
// 451.970 us; speedup vs baseline: 1.0366x; 1.0236x over previous
//
#include <hip/hip_runtime.h>
#include <hip/hip_bf16.h>
#include <stdint.h>

#define NN 3072
#define EE 49152
#define DD 256
#define OO 512
#define HH 8
#define DHH 32
#define NETT 5
#define NC 8
#define NCMAX 512  // community size cap (multinomial mean 384, sigma 18 -> +7 sigma)
#define SCP 516    // sc row stride (516*4B = 2064B, 16B-aligned)
#define KS 16      // key splits: 768 blocks = 3/CU exactly
#define NW 17      // weight matrices (16x 256x256 + 1x 256x512)

typedef __attribute__((ext_vector_type(8))) short short8;
typedef __attribute__((ext_vector_type(4))) short short4v;
typedef __attribute__((ext_vector_type(4))) float f32x4;

__device__ __forceinline__ short f2bf_s(float f){
    __hip_bfloat16 h = __float2bfloat16(f);
    return *reinterpret_cast<short*>(&h);
}
__device__ __forceinline__ float bf2f_s(short v){
    __hip_bfloat16 h;
    *reinterpret_cast<short*>(&h) = v;
    return __bfloat162float(h);
}

// ---------------- embedding (+ bf16 A-operand precompute) ----------------
// Standalone 3072-block kernel (r9's fusion into wtrans serialized it; r10 reverted).
__global__ void k_embed(const float* __restrict__ x, const float* __restrict__ w,
                        const float* __restrict__ b, const float* __restrict__ pos,
                        float* __restrict__ h, short* __restrict__ hbf, short* __restrict__ hpbf){
    int i = blockIdx.x * 256 + threadIdx.x;
    int n = i >> 8, d = i & 255;
    float v = x[n] * w[d] + b[d];
    h[i] = v;
    hbf[i] = f2bf_s(v);
    hpbf[i] = f2bf_s(v + pos[i]);   // bf16(h+pos): identical to old in-GEMM f32 add+cast
}

// ---------------- batched weight transpose+cast ----------------
struct WT {
    const float* src[NW];
    short*       dst[NW];
    int          M[NW];
};
__global__ __launch_bounds__(256) void k_wtrans(WT wt){
    int id = blockIdx.z;
    int M = wt.M[id];
    int bx = blockIdx.x;
    if (bx * 32 >= M) return;
    int by = blockIdx.y;
    __shared__ float t[32][33];
    int lx = threadIdx.x & 31, ly = threadIdx.x >> 5;
    const float* w = wt.src[id];
    for (int i = ly; i < 32; i += 8)
        t[i][lx] = w[(size_t)(by * 32 + i) * M + bx * 32 + lx];
    __syncthreads();
    short* d = wt.dst[id];
    for (int r = ly; r < 32; r += 8)
        d[(size_t)(bx * 32 + r) * DD + by * 32 + lx] = f2bf_s(t[lx][r]);
}

// ---------------- CSR build + community sort (r11: fused trio, embed NOT fused) ----------------
// r9 proved these correct; r9's regression was the embed fusion (serialized
// tail), not these. Same atomics, same dependency order, -3 dispatches.
__global__ void k_count2(const int* __restrict__ ei, const int* __restrict__ comm,
                         int* __restrict__ cnt, int* __restrict__ ccnt){
    int e = blockIdx.x * 256 + threadIdx.x;
    if (e < EE) atomicAdd(&cnt[ei[e]], 1);
    if (e < NN) atomicAdd(&ccnt[comm[e]], 1);
}

__global__ void k_scan2(const int* __restrict__ cnt, int* __restrict__ rp,
                        const int* __restrict__ ccnt, int* __restrict__ cstart){
    __shared__ int part[256];
    int tid = threadIdx.x;
    int base = tid * 12;
    int loc[12]; int s = 0;
    for (int i = 0; i < 12; i++){ loc[i] = s; s += cnt[base + i]; }
    part[tid] = s; __syncthreads();
    if (tid == 0){ int a = 0; for (int i = 0; i < 256; i++){ int t = part[i]; part[i] = a; a += t; } }
    __syncthreads();
    int b = part[tid];
    for (int i = 0; i < 12; i++) rp[base + i] = b + loc[i];
    if (tid == 255) rp[NN] = b + s;
    if (tid == 0){
        cstart[0] = 0;
        for (int c = 0; c < NC; c++) cstart[c + 1] = cstart[c] + ccnt[c];
    }
}

__global__ void k_fill2(const int* __restrict__ ei, const int* __restrict__ et,
                        const int* __restrict__ rp, int* __restrict__ cur,
                        int* __restrict__ e_dst, int* __restrict__ e_typ,
                        const int* __restrict__ comm, const int* __restrict__ cstart,
                        int* __restrict__ ccur, int* __restrict__ perm, int* __restrict__ inv){
    int e = blockIdx.x * 256 + threadIdx.x;
    if (e < EE){
        int s = ei[e], d = ei[EE + e];
        int p = atomicAdd(&cur[s], 1);
        int idx = rp[s] + p;
        e_dst[idx] = d; e_typ[idx] = et[e];
    }
    if (e < NN){
        int c = comm[e];
        int p = cstart[c] + atomicAdd(&ccur[c], 1);
        perm[p] = e; inv[e] = p;
    }
}

// ---------------- MFMA GEMM (bf16 A): C[m][n] = A @ W + bias ----------------
template<int M>
__global__ __launch_bounds__(256) void k_gemm_mfma(
        const short* __restrict__ A, const short* __restrict__ Wt,
        const float* __restrict__ bias, float* __restrict__ C){
    int tid = threadIdx.x;
    int w = tid >> 6, lane = tid & 63, quad = lane >> 4, col = lane & 15;
    int m0 = blockIdx.x * 64 + w * 16;
    int n0 = blockIdx.y * 64;

    const short* arow = A + (size_t)(m0 + col) * DD;

    f32x4 acc[4];
    #pragma unroll
    for (int su = 0; su < 4; su++) acc[su] = (f32x4){0.f, 0.f, 0.f, 0.f};

    #pragma unroll
    for (int f = 0; f < 8; f++){
        int k0 = f * 32 + quad * 8;
        short8 af = *(const short8*)(arow + k0);
        #pragma unroll
        for (int su = 0; su < 4; su++){
            short8 bf = *(const short8*)(Wt + (size_t)(n0 + su * 16 + col) * DD + k0);
            acc[su] = __builtin_amdgcn_mfma_f32_16x16x32_bf16(af, bf, acc[su], 0, 0, 0);
        }
    }

    #pragma unroll
    for (int su = 0; su < 4; su++){
        int n = n0 + su * 16 + col;
        float bz = bias[n];
        #pragma unroll
        for (int r = 0; r < 4; r++)
            C[(size_t)(m0 + quad * 4 + r) * M + n] = acc[su][r] + bz;
    }
}

// ---------------- fused QKV MFMA GEMM (bf16 A) ----------------
// r4/r5: V-transpose fused. z==2 writes V^T[n][m] directly as packed short4.
// For local layers A-rows are gathered via perm so m IS the sorted position.
struct QKV {
    const short* Wt[3];
    const float* bias[3];
    short*       Cb[2];    // Q, K row-major bf16 outs
    short*       VtOut;    // V^T [DD][NN] bf16
};
__global__ __launch_bounds__(256) void k_gemm_qkv(
        const short* __restrict__ A, QKV q, const int* __restrict__ permRow){
    int z = blockIdx.z;
    const short* Wt = q.Wt[z];
    const float* bias = q.bias[z];

    int tid = threadIdx.x;
    int w = tid >> 6, lane = tid & 63, quad = lane >> 4, col = lane & 15;
    int m0 = blockIdx.x * 64 + w * 16;
    int n0 = blockIdx.y * 64;

    int arowIdx = m0 + col;
    if (permRow) arowIdx = permRow[arowIdx];
    const short* arow = A + (size_t)arowIdx * DD;

    f32x4 acc[4];
    #pragma unroll
    for (int su = 0; su < 4; su++) acc[su] = (f32x4){0.f, 0.f, 0.f, 0.f};

    #pragma unroll
    for (int f = 0; f < 8; f++){
        int k0 = f * 32 + quad * 8;
        short8 af = *(const short8*)(arow + k0);
        #pragma unroll
        for (int su = 0; su < 4; su++){
            short8 bf = *(const short8*)(Wt + (size_t)(n0 + su * 16 + col) * DD + k0);
            acc[su] = __builtin_amdgcn_mfma_f32_16x16x32_bf16(af, bf, acc[su], 0, 0, 0);
        }
    }

    if (z == 2){
        // V^T: for fixed n, the 4 r-values are m-consecutive -> packed short4
        #pragma unroll
        for (int su = 0; su < 4; su++){
            int n = n0 + su * 16 + col;
            float bz = bias[n];
            short4v pk;
            #pragma unroll
            for (int r = 0; r < 4; r++) pk[r] = f2bf_s(acc[su][r] + bz);
            *(short4v*)(q.VtOut + (size_t)n * NN + m0 + quad * 4) = pk;
        }
    } else {
        short* Cb = q.Cb[z];
        #pragma unroll
        for (int su = 0; su < 4; su++){
            int n = n0 + su * 16 + col;
            float bz = bias[n];
            #pragma unroll
            for (int r = 0; r < 4; r++)
                Cb[(size_t)(m0 + quad * 4 + r) * DD + n] = f2bf_s(acc[su][r] + bz);
        }
    }
}

// ---------------- fused O-proj GEMM + residual + LayerNorm ----------------
// r6: template<MERGE>. MERGE=1 (global layers) fuses the old k_gmerge.
template<int MERGE>
__global__ __launch_bounds__(256) void k_gemm_o_ln(
        const short* __restrict__ A,
        const short* __restrict__ Opart, const float* __restrict__ lpart,
        const short* __restrict__ Wt, const float* __restrict__ bias,
        const float* __restrict__ g, const float* __restrict__ b,
        const float* __restrict__ pos,
        float* __restrict__ h, short* __restrict__ hbf, short* __restrict__ hpbf){
    __shared__ float t[16][258];                 // 16.5 KB
    __shared__ short Al[MERGE ? 16 * 256 : 1];   // 8 KB (MERGE only)
    __shared__ float lsum[MERGE ? 16 : 1];
    int tid = threadIdx.x;
    int w = tid >> 6, lane = tid & 63, quad = lane >> 4, col = lane & 15;
    int m0 = blockIdx.x * 16;
    int n0 = w * 64;

    const short* arow = A ? A + (size_t)(m0 + col) * DD : nullptr;

    if (MERGE){
        if (tid < 16){
            float l = 0.f;
            for (int s = 0; s < KS; s++) l += lpart[s * NN + m0 + tid];
            lsum[tid] = l;
        }
        __syncthreads();
        #pragma unroll
        for (int i = 0; i < 2; i++){
            int c = tid + i * 256;               // 512 chunks of short8
            int row = c >> 5, seg = c & 31;
            const short* src = Opart + (size_t)(m0 + row) * DD + seg * 8;
            float v[8] = {0.f,0.f,0.f,0.f,0.f,0.f,0.f,0.f};
            for (int s = 0; s < KS; s++){
                short8 o = *(const short8*)(src + (size_t)s * NN * DD);
                #pragma unroll
                for (int j = 0; j < 8; j++) v[j] += bf2f_s(o[j]);
            }
            float lr = lsum[row];
            short8 res;
            #pragma unroll
            for (int j = 0; j < 8; j++) res[j] = f2bf_s(v[j] / lr);
            *(short8*)&Al[(row << 8) + ((seg * 8) ^ ((row & 7) << 3))] = res;
        }
        __syncthreads();
    }

    f32x4 acc[4];
    #pragma unroll
    for (int su = 0; su < 4; su++) acc[su] = (f32x4){0.f, 0.f, 0.f, 0.f};

    #pragma unroll
    for (int f = 0; f < 8; f++){
        int k0 = f * 32 + quad * 8;
        short8 af;
        if (MERGE) af = *(const short8*)&Al[(col << 8) + (k0 ^ ((col & 7) << 3))];
        else       af = *(const short8*)(arow + k0);
        #pragma unroll
        for (int su = 0; su < 4; su++){
            short8 bf = *(const short8*)(Wt + (size_t)(n0 + su * 16 + col) * DD + k0);
            acc[su] = __builtin_amdgcn_mfma_f32_16x16x32_bf16(af, bf, acc[su], 0, 0, 0);
        }
    }

    #pragma unroll
    for (int su = 0; su < 4; su++){
        int n = n0 + su * 16 + col;
        float bz = bias[n];
        #pragma unroll
        for (int r = 0; r < 4; r++)
            t[quad * 4 + r][n] = acc[su][r] + bz;
    }
    __syncthreads();

    // ---- residual + LN: row = tid>>4, 16 lanes per row, 16 d's per lane
    int row = tid >> 4, l16 = tid & 15;
    int m = m0 + row;
    float v[16];
    float s = 0.f;
    #pragma unroll
    for (int j = 0; j < 16; j++){
        int d = l16 + j * 16;
        float vv = t[row][d] + h[(size_t)m * DD + d];
        v[j] = vv; s += vv;
    }
    #pragma unroll
    for (int off = 1; off < 16; off <<= 1) s += __shfl_xor(s, off);
    float mean = s * (1.0f / 256.0f);
    float s2 = 0.f;
    #pragma unroll
    for (int j = 0; j < 16; j++){ float c = v[j] - mean; s2 += c * c; }
    #pragma unroll
    for (int off = 1; off < 16; off <<= 1) s2 += __shfl_xor(s2, off);
    float rstd = rsqrtf(s2 * (1.0f / 256.0f) + 1e-5f);
    #pragma unroll
    for (int j = 0; j < 16; j++){
        int d = l16 + j * 16;
        float out = (v[j] - mean) * rstd * g[d] + b[d];
        size_t idx = (size_t)m * DD + d;
        h[idx] = out;
        hbf[idx] = f2bf_s(out);
        if (pos) hpbf[idx] = f2bf_s(out + pos[idx]);
    }
}

// ---------------- local attention v6 (r8-proven; r10's v7 prefetch was noise-negative) ----------------
__global__ __launch_bounds__(256) void k_local_attn6(
        const short* __restrict__ Qs, const short* __restrict__ Ks, const short* __restrict__ Vts,
        const int* __restrict__ cstart, const int* __restrict__ perm, const int* __restrict__ inv,
        const int* __restrict__ rp, const int* __restrict__ e_dst, const int* __restrict__ e_typ,
        const float* __restrict__ eb, short* __restrict__ obbf){
    int c  = blockIdx.y;
    int hh = blockIdx.z;
    int cs0 = cstart[c], cs1 = cstart[c + 1];
    int Nc = cs1 - cs0;
    int p0 = blockIdx.x * 16;
    if (p0 >= Nc) return;
    int tid = threadIdx.x;
    int w = tid >> 6, lane = tid & 63, quad = lane >> 4, col = lane & 15;
    int nt  = (Nc + 15) >> 4;
    int nt2 = (Nc + 31) >> 5;

    __shared__ float sc[16][SCP];
    __shared__ float linv[16];
    __shared__ int qnode[16];

    if (tid < 16) qnode[tid] = (p0 + tid < Nc) ? perm[cs0 + p0 + tid] : -1;

    int qrow = cs0 + min(p0 + col, Nc - 1);
    short8 qf = *(const short8*)(Qs + (size_t)qrow * DD + hh * DHH + quad * 8);

    const float scale = 0.17677669529663687f; // 1/sqrt(32)

    for (int t = w; t < nt; t += 4){
        int kt = t * 16;
        int krow = cs0 + min(kt + col, Nc - 1);
        short8 kf = *(const short8*)(Ks + (size_t)krow * DD + hh * DHH + quad * 8);
        f32x4 s = __builtin_amdgcn_mfma_f32_16x16x32_bf16(qf, kf, (f32x4){0.f,0.f,0.f,0.f}, 0, 0, 0);
        #pragma unroll
        for (int r = 0; r < 4; r++)
            sc[quad * 4 + r][kt + col] = s[r] * scale;
    }
    __syncthreads();

    int qi = tid >> 4, l16 = tid & 15;
    {
        int n = qnode[qi];
        if (n >= 0){
            int re = rp[n + 1];
            for (int e2 = rp[n] + l16; e2 < re; e2 += 16){
                int dpos = inv[e_dst[e2]];
                if (dpos >= cs0 && dpos < cs1)
                    atomicAdd(&sc[qi][dpos - cs0], eb[e_typ[e2] * HH + hh]);
            }
        }
    }
    __syncthreads();

    {
        float lm = -1e30f;
        for (int m = l16; m < Nc; m += 16) lm = fmaxf(lm, sc[qi][m]);
        #pragma unroll
        for (int off = 1; off < 16; off <<= 1) lm = fmaxf(lm, __shfl_xor(lm, off));
        float ls = 0.f;
        for (int m = l16; m < Nc; m += 16){
            float e_ = __expf(sc[qi][m] - lm);
            sc[qi][m] = e_;
            ls += e_;
        }
        for (int m = (Nc & ~15) + l16; m < nt2 * 32; m += 16)
            if (m >= Nc) sc[qi][m] = 0.f;
        #pragma unroll
        for (int off = 1; off < 16; off <<= 1) ls += __shfl_xor(ls, off);
        if (l16 == 0) linv[qi] = 1.f / ls;
    }
    __syncthreads();

    f32x4 acc0 = (f32x4){0.f,0.f,0.f,0.f}, acc1 = (f32x4){0.f,0.f,0.f,0.f};
    for (int t2 = w; t2 < nt2; t2 += 4){
        int kt = t2 * 32;
        float4 pa = *(const float4*)&sc[col][kt + quad * 8];
        float4 pb = *(const float4*)&sc[col][kt + quad * 8 + 4];
        short8 pf;
        pf[0] = f2bf_s(pa.x); pf[1] = f2bf_s(pa.y); pf[2] = f2bf_s(pa.z); pf[3] = f2bf_s(pa.w);
        pf[4] = f2bf_s(pb.x); pf[5] = f2bf_s(pb.y); pf[6] = f2bf_s(pb.z); pf[7] = f2bf_s(pb.w);
        const short* vb0 = Vts + (size_t)(hh * DHH + col) * NN + cs0 + kt + quad * 8;
        short8 vf0 = *(const short8*)(vb0);
        short8 vf1 = *(const short8*)(vb0 + (size_t)16 * NN);
        acc0 = __builtin_amdgcn_mfma_f32_16x16x32_bf16(pf, vf0, acc0, 0, 0, 0);
        acc1 = __builtin_amdgcn_mfma_f32_16x16x32_bf16(pf, vf1, acc1, 0, 0, 0);
    }
    __syncthreads();   // all waves done READING sc -> safe to alias as pv
    {
        float (*pv)[16][33] = reinterpret_cast<float (*)[16][33]>(&sc[0][0]); // 8.45KB < 33KB
        #pragma unroll
        for (int r = 0; r < 4; r++){
            pv[w][quad * 4 + r][col]      = acc0[r];
            pv[w][quad * 4 + r][col + 16] = acc1[r];
        }
        __syncthreads();

        int q = tid >> 4, d0 = tid & 15;
        int n = qnode[q];
        #pragma unroll
        for (int half = 0; half < 2; half++){
            int dd = d0 + half * 16;
            float sum = pv[0][q][dd] + pv[1][q][dd] + pv[2][q][dd] + pv[3][q][dd];
            if (n >= 0) obbf[(size_t)n * DD + hh * DHH + dd] = f2bf_s(sum * linv[q]);
        }
    }
}

// ---------------- global attention v10+ (r8-proven, unchanged) ----------------
__global__ __launch_bounds__(256) void k_glob_mfma10(
        const short* __restrict__ Qb, const short* __restrict__ Kb,
        const short* __restrict__ Vt, const int* __restrict__ comm,
        short* __restrict__ Opart, float* __restrict__ lpart){
    int tid = threadIdx.x;
    int w = tid >> 6, lane = tid & 63, quad = lane >> 4, col = lane & 15;
    int qt = blockIdx.x * 64 + w * 16;
    int split = blockIdx.y;
    int ks0 = split * (NN / KS);   // 192 keys/split
    const int NT = NN / KS / 32;   // 6 key tiles

    __shared__ __align__(16) short Kl[32 * 256];  // 16.0 KB, XOR-swizzled
    __shared__ __align__(16) short Vl[256][40];   // 20.5 KB, V^T tile [d][key]
    __shared__ __align__(16) short Pl[4][16][40]; // 5.1 KB, per-wave P tiles

    short8 qf[8];
    #pragma unroll
    for (int f = 0; f < 8; f++)
        qf[f] = *(const short8*)(Qb + (size_t)(qt + col) * DD + f * 32 + quad * 8);

    int qc[4];
    #pragma unroll
    for (int r = 0; r < 4; r++) qc[r] = comm[qt + quad * 4 + r];

    f32x4 accO[16];
    #pragma unroll
    for (int dt = 0; dt < 16; dt++) accO[dt] = (f32x4){0.f, 0.f, 0.f, 0.f};
    float l_[4] = {0.f, 0.f, 0.f, 0.f};

    const float scale = 0.17677669529663687f; // 1/sqrt(32) per reference

    // per-thread staging geometry (chunk idx = tid + i*256)
    int ksg = tid & 31;            // K: 16B chunk within row
    int kr0 = tid >> 5;            // K: base row (+8 per i) -> (row&7) const per thread
    int ksw = (kr0 & 7) << 3;      // swizzle XOR, in shorts
    int vsg = tid & 3;             // V: chunk within d-row
    int vd0 = tid >> 2;            // V: base d (+64 per i)

    short8 kpre[4], vpre[4];
    #pragma unroll
    for (int i = 0; i < 4; i++){
        kpre[i] = *(const short8*)(Kb + (size_t)(ks0 + kr0 + 8 * i) * DD + ksg * 8);
        vpre[i] = *(const short8*)(Vt + (size_t)(vd0 + 64 * i) * NN + ks0 + vsg * 8);
    }
    int cm0n = comm[ks0 + col];
    int cm1n = comm[ks0 + 16 + col];

    for (int t = 0; t < NT; t++){
        int kt = ks0 + t * 32;
        __syncthreads();           // prev iteration's LDS reads complete
        #pragma unroll
        for (int i = 0; i < 4; i++){
            *(short8*)&Kl[(kr0 + 8 * i) * 256 + ((ksg * 8) ^ ksw)] = kpre[i];
            *(short8*)&Vl[vd0 + 64 * i][vsg * 8] = vpre[i];
        }
        __syncthreads();
        int cm0 = cm0n, cm1 = cm1n;
        if (t + 1 < NT){           // prefetch next tile; hides under MFMA below
            int kn = kt + 32;
            #pragma unroll
            for (int i = 0; i < 4; i++){
                kpre[i] = *(const short8*)(Kb + (size_t)(kn + kr0 + 8 * i) * DD + ksg * 8);
                vpre[i] = *(const short8*)(Vt + (size_t)(vd0 + 64 * i) * NN + kn + vsg * 8);
            }
            cm0n = comm[kn + col];
            cm1n = comm[kn + 16 + col];
        }

        // ---- S: 16 q x 32 keys from swizzled LDS frags
        f32x4 s0 = (f32x4){0.f,0.f,0.f,0.f}, s1 = (f32x4){0.f,0.f,0.f,0.f};
        int csw = (col & 7) << 3;  // (16+col)&7 == col&7
        #pragma unroll
        for (int f = 0; f < 8; f++){
            int cs = (f * 32 + quad * 8) ^ csw;
            short8 kf0 = *(const short8*)&Kl[col * 256 + cs];
            short8 kf1 = *(const short8*)&Kl[(16 + col) * 256 + cs];
            s0 = __builtin_amdgcn_mfma_f32_16x16x32_bf16(qf[f], kf0, s0, 0, 0, 0);
            s1 = __builtin_amdgcn_mfma_f32_16x16x32_bf16(qf[f], kf1, s1, 0, 0, 0);
        }

        #pragma unroll
        for (int r = 0; r < 4; r++){
            float p0 = (cm0 != qc[r]) ? __expf(s0[r] * scale) : 0.f;
            float p1 = (cm1 != qc[r]) ? __expf(s1[r] * scale) : 0.f;
            l_[r] += p0 + p1;
            int row = quad * 4 + r;
            Pl[w][row][col]      = f2bf_s(p0);
            Pl[w][row][col + 16] = f2bf_s(p1);
        }
        short8 pf = *(const short8*)(&Pl[w][col][quad * 8]);
        // ---- PV: V frags from LDS
        #pragma unroll
        for (int dt = 0; dt < 16; dt++){
            short8 vf = *(const short8*)&Vl[dt * 16 + col][quad * 8];
            accO[dt] = __builtin_amdgcn_mfma_f32_16x16x32_bf16(pf, vf, accO[dt], 0, 0, 0);
        }
    }

    #pragma unroll
    for (int r = 0; r < 4; r++){
        float vv = l_[r];
        #pragma unroll
        for (int off = 1; off < 16; off <<= 1) vv += __shfl_xor(vv, off);
        l_[r] = vv;
    }

    #pragma unroll
    for (int r = 0; r < 4; r++){
        int row = qt + quad * 4 + r;
        if (col == 0) lpart[split * NN + row] = l_[r];
        #pragma unroll
        for (int dt = 0; dt < 16; dt++)
            Opart[((size_t)split * NN + row) * DD + dt * 16 + col] = f2bf_s(accO[dt][r]);
    }
}

// ---------------- host ----------------
extern "C" void kernel_launch(void* const* d_in, const int* in_sizes, int n_in,
                              void* d_out, int out_size, void* d_ws, size_t ws_size,
                              hipStream_t stream){
    const float* x        = (const float*)d_in[0];
    const int*   ei       = (const int*)  d_in[1];
    const int*   et       = (const int*)  d_in[2];
    const float* pos      = (const float*)d_in[3];
    const int*   comm     = (const int*)  d_in[4];
    const float* emb_w    = (const float*)d_in[6];
    const float* emb_b    = (const float*)d_in[7];
    const float* loc_qw   = (const float*)d_in[8];
    const float* loc_qb   = (const float*)d_in[9];
    const float* loc_kw   = (const float*)d_in[10];
    const float* loc_kb   = (const float*)d_in[11];
    const float* loc_vw   = (const float*)d_in[12];
    const float* loc_vb   = (const float*)d_in[13];
    const float* loc_ow   = (const float*)d_in[14];
    const float* loc_ob   = (const float*)d_in[15];
    const float* loc_eb   = (const float*)d_in[16];
    const float* loc_ln_g = (const float*)d_in[17];
    const float* loc_ln_b = (const float*)d_in[18];
    const float* glob_qw  = (const float*)d_in[19];
    const float* glob_qb  = (const float*)d_in[20];
    const float* glob_kw  = (const float*)d_in[21];
    const float* glob_kb  = (const float*)d_in[22];
    const float* glob_vw  = (const float*)d_in[23];
    const float* glob_vb  = (const float*)d_in[24];
    const float* glob_ow  = (const float*)d_in[25];
    const float* glob_ob  = (const float*)d_in[26];
    const float* glob_ln_g= (const float*)d_in[27];
    const float* glob_ln_b= (const float*)d_in[28];
    const float* out_w    = (const float*)d_in[29];
    const float* out_b    = (const float*)d_in[30];

    float* h    = (float*)d_ws;           // NN*DD f32
    float* lpart= h + NN * DD;            // KS*NN
    int* cnt    = (int*)(lpart + KS * NN);
    int* cur    = cnt + NN;
    int* ccnt   = cur + NN;
    int* ccur   = ccnt + NC;
    int* cstart = ccur + NC;
    int* rp     = cstart + NC + 1;
    int* perm   = rp + NN + 1;
    int* inv    = perm + NN;
    int* e_dst  = inv + NN;
    int* e_typ  = e_dst + EE;
    short* Qbf  = (short*)(((uintptr_t)(e_typ + EE) + 15) & ~(uintptr_t)15);
    short* Kbf  = Qbf + NN * DD;
    short* Vt   = Kbf + NN * DD;          // [DD][NN]
    short* WtAll= Vt + (size_t)DD * NN;   // 16*65536 + 131072 shorts
    short* Qs   = WtAll + 16 * DD * DD + DD * OO;  // sorted bf16 Q [NN][DD]
    short* Ks2  = Qs + (size_t)NN * DD;            // sorted bf16 K
    short* Vts  = Ks2 + (size_t)NN * DD;           // sorted V^T [DD][NN]
    short* Opart= Vts + (size_t)DD * NN;           // KS*NN*DD bf16
    short* hbf  = Opart + (size_t)KS * NN * DD;    // bf16(h)
    short* hpbf = hbf + (size_t)NN * DD;           // bf16(h+pos)
    short* obbf = hpbf + (size_t)NN * DD;          // bf16 attn output (local GEMM A)

    WT wt;
    const float* wsrc[NW] = {
        loc_qw, loc_kw, loc_vw, loc_ow,
        loc_qw + DD * DD, loc_kw + DD * DD, loc_vw + DD * DD, loc_ow + DD * DD,
        glob_qw, glob_kw, glob_vw, glob_ow,
        glob_qw + DD * DD, glob_kw + DD * DD, glob_vw + DD * DD, glob_ow + DD * DD,
        out_w };
    for (int i = 0; i < NW; i++){
        wt.src[i] = wsrc[i];
        wt.dst[i] = WtAll + (size_t)i * DD * DD;
        wt.M[i]   = (i == 16) ? OO : DD;
    }
    short* WtLQ[2] = { WtAll + 0 * DD * DD, WtAll + 4 * DD * DD };
    short* WtLK[2] = { WtAll + 1 * DD * DD, WtAll + 5 * DD * DD };
    short* WtLV[2] = { WtAll + 2 * DD * DD, WtAll + 6 * DD * DD };
    short* WtLO[2] = { WtAll + 3 * DD * DD, WtAll + 7 * DD * DD };
    short* WtGQ[2] = { WtAll + 8 * DD * DD, WtAll + 12 * DD * DD };
    short* WtGK[2] = { WtAll + 9 * DD * DD, WtAll + 13 * DD * DD };
    short* WtGV[2] = { WtAll + 10 * DD * DD, WtAll + 14 * DD * DD };
    short* WtGO[2] = { WtAll + 11 * DD * DD, WtAll + 15 * DD * DD };
    short* WtOut   = WtAll + 16 * DD * DD;

    (void)hipMemsetAsync(cnt, 0, sizeof(int) * (2 * NN + 2 * NC), stream);

    k_embed<<<NN * DD / 256, 256, 0, stream>>>(x, emb_w, emb_b, pos, h, hbf, hpbf);
    k_wtrans<<<dim3(16, 8, NW), 256, 0, stream>>>(wt);
    k_count2<<<EE / 256, 256, 0, stream>>>(ei, comm, cnt, ccnt);
    k_scan2<<<1, 256, 0, stream>>>(cnt, rp, ccnt, cstart);
    k_fill2<<<EE / 256, 256, 0, stream>>>(ei, et, rp, cur, e_dst, e_typ,
                                          comm, cstart, ccur, perm, inv);

    for (int l = 0; l < 2; l++){
        QKV q;
        q.Wt[0] = WtLQ[l]; q.Wt[1] = WtLK[l]; q.Wt[2] = WtLV[l];
        q.bias[0] = loc_qb + l * DD; q.bias[1] = loc_kb + l * DD; q.bias[2] = loc_vb + l * DD;
        q.Cb[0] = Qs; q.Cb[1] = Ks2;
        q.VtOut = Vts;
        // A-rows permuted -> outputs land directly in sorted space
        k_gemm_qkv<<<dim3(NN / 64, DD / 64, 3), 256, 0, stream>>>(hpbf, q, perm);
        k_local_attn6<<<dim3(NCMAX / 16, NC, HH), 256, 0, stream>>>(
            Qs, Ks2, Vts, cstart, perm, inv, rp, e_dst, e_typ,
            loc_eb + l * NETT * HH, obbf);
        k_gemm_o_ln<0><<<NN / 16, 256, 0, stream>>>(
            obbf, nullptr, nullptr,
            WtLO[l], loc_ob + l * DD, loc_ln_g + l * DD, loc_ln_b + l * DD,
            (l == 0) ? pos : nullptr, h, hbf, hpbf);
    }

    for (int g = 0; g < 2; g++){
        QKV q;
        q.Wt[0] = WtGQ[g]; q.Wt[1] = WtGK[g]; q.Wt[2] = WtGV[g];
        q.bias[0] = glob_qb + g * DD; q.bias[1] = glob_kb + g * DD; q.bias[2] = glob_vb + g * DD;
        q.Cb[0] = Qbf; q.Cb[1] = Kbf;
        q.VtOut = Vt;
        k_gemm_qkv<<<dim3(NN / 64, DD / 64, 3), 256, 0, stream>>>(hbf, q, nullptr);
        k_glob_mfma10<<<dim3(NN / 64, KS), 256, 0, stream>>>(Qbf, Kbf, Vt, comm, Opart, lpart);
        k_gemm_o_ln<1><<<NN / 16, 256, 0, stream>>>(
            nullptr, Opart, lpart,
            WtGO[g], glob_ob + g * DD, glob_ln_g + g * DD, glob_ln_b + g * DD,
            nullptr, h, hbf, nullptr);
    }

    k_gemm_mfma<OO><<<dim3(NN / 64, OO / 64), 256, 0, stream>>>(hbf, WtOut, out_b, (float*)d_out);
}

// Round 13
// 446.971 us; speedup vs baseline: 1.0482x; 1.0112x over previous
//
#include <hip/hip_runtime.h>
#include <hip/hip_bf16.h>
#include <stdint.h>

#define NN 3072
#define EE 49152
#define DD 256
#define OO 512
#define HH 8
#define DHH 32
#define NETT 5
#define NC 8
#define NCMAX 512  // community size cap (multinomial mean 384, sigma 18 -> +7 sigma)
#define SCP 516    // sc row stride (516*4B = 2064B, 16B-aligned)
#define KS 16      // key splits: 768 blocks = 3/CU exactly
#define NW 17      // weight matrices (16x 256x256 + 1x 256x512)

// mega-preproc block-range partition (r13): tasks independent, full parallelism each
#define PRE_EMBED 3072              // NN*DD/256
#define PRE_WT    2176              // 16*8*NW
#define PRE_CNT   192               // EE/256

typedef __attribute__((ext_vector_type(8))) short short8;
typedef __attribute__((ext_vector_type(4))) short short4v;
typedef __attribute__((ext_vector_type(4))) float f32x4;

__device__ __forceinline__ short f2bf_s(float f){
    __hip_bfloat16 h = __float2bfloat16(f);
    return *reinterpret_cast<short*>(&h);
}
__device__ __forceinline__ float bf2f_s(short v){
    __hip_bfloat16 h;
    *reinterpret_cast<short*>(&h) = v;
    return __bfloat162float(h);
}

// ---------------- mega preproc: embed ∥ wtrans ∥ count2 (r13) ----------------
// r9's failed fusion grid-strided embed on 128 blocks (serialized tail).
// Here each task keeps its ORIGINAL block count; blockIdx.x picks the task
// (block-uniform branch -> wtrans __syncthreads safe). Tasks touch disjoint
// memory. memset of cnt/ccnt stays BEFORE this kernel (count2 atomics).
struct PRE {
    // wtrans
    const float* src[NW];
    short*       dst[NW];
    int          M[NW];
    // embed
    const float* x; const float* emb_w; const float* emb_b; const float* pos;
    float* h; short* hbf; short* hpbf;
    // count2
    const int* ei; const int* comm;
    int* cnt; int* ccnt;
};
__global__ __launch_bounds__(256) void k_preproc(PRE p){
    __shared__ float t[32][33];
    int b = blockIdx.x, tid = threadIdx.x;
    if (b < PRE_EMBED){
        int i = b * 256 + tid;
        int n = i >> 8, d = i & 255;
        float v = p.x[n] * p.emb_w[d] + p.emb_b[d];
        p.h[i] = v;
        p.hbf[i] = f2bf_s(v);
        p.hpbf[i] = f2bf_s(v + p.pos[i]);
        return;
    }
    if (b < PRE_EMBED + PRE_WT){
        int bb = b - PRE_EMBED;
        int id = bb >> 7;                 // 0..NW-1
        int rem = bb & 127;
        int bx = rem & 15, by = rem >> 4; // bx: M tile, by: k tile
        int M = p.M[id];
        if (bx * 32 >= M) return;
        int lx = tid & 31, ly = tid >> 5;
        const float* w = p.src[id];
        for (int i = ly; i < 32; i += 8)
            t[i][lx] = w[(size_t)(by * 32 + i) * M + bx * 32 + lx];
        __syncthreads();
        short* d = p.dst[id];
        for (int r = ly; r < 32; r += 8)
            d[(size_t)(bx * 32 + r) * DD + by * 32 + lx] = f2bf_s(t[lx][r]);
        return;
    }
    int e = (b - PRE_EMBED - PRE_WT) * 256 + tid;
    if (e < EE) atomicAdd(&p.cnt[p.ei[e]], 1);
    if (e < NN) atomicAdd(&p.ccnt[p.comm[e]], 1);
}

// ---------------- scan (rp block-scan + cstart serial) ----------------
__global__ void k_scan2(const int* __restrict__ cnt, int* __restrict__ rp,
                        const int* __restrict__ ccnt, int* __restrict__ cstart){
    __shared__ int part[256];
    int tid = threadIdx.x;
    int base = tid * 12;
    int loc[12]; int s = 0;
    for (int i = 0; i < 12; i++){ loc[i] = s; s += cnt[base + i]; }
    part[tid] = s; __syncthreads();
    if (tid == 0){ int a = 0; for (int i = 0; i < 256; i++){ int t = part[i]; part[i] = a; a += t; } }
    __syncthreads();
    int b = part[tid];
    for (int i = 0; i < 12; i++) rp[base + i] = b + loc[i];
    if (tid == 255) rp[NN] = b + s;
    if (tid == 0){
        cstart[0] = 0;
        for (int c = 0; c < NC; c++) cstart[c + 1] = cstart[c] + ccnt[c];
    }
}

__global__ void k_fill2(const int* __restrict__ ei, const int* __restrict__ et,
                        const int* __restrict__ rp, int* __restrict__ cur,
                        int* __restrict__ e_dst, int* __restrict__ e_typ,
                        const int* __restrict__ comm, const int* __restrict__ cstart,
                        int* __restrict__ ccur, int* __restrict__ perm, int* __restrict__ inv){
    int e = blockIdx.x * 256 + threadIdx.x;
    if (e < EE){
        int s = ei[e], d = ei[EE + e];
        int p = atomicAdd(&cur[s], 1);
        int idx = rp[s] + p;
        e_dst[idx] = d; e_typ[idx] = et[e];
    }
    if (e < NN){
        int c = comm[e];
        int p = cstart[c] + atomicAdd(&ccur[c], 1);
        perm[p] = e; inv[e] = p;
    }
}

// ---------------- MFMA GEMM (bf16 A): C[m][n] = A @ W + bias ----------------
template<int M>
__global__ __launch_bounds__(256) void k_gemm_mfma(
        const short* __restrict__ A, const short* __restrict__ Wt,
        const float* __restrict__ bias, float* __restrict__ C){
    int tid = threadIdx.x;
    int w = tid >> 6, lane = tid & 63, quad = lane >> 4, col = lane & 15;
    int m0 = blockIdx.x * 64 + w * 16;
    int n0 = blockIdx.y * 64;

    const short* arow = A + (size_t)(m0 + col) * DD;

    f32x4 acc[4];
    #pragma unroll
    for (int su = 0; su < 4; su++) acc[su] = (f32x4){0.f, 0.f, 0.f, 0.f};

    #pragma unroll
    for (int f = 0; f < 8; f++){
        int k0 = f * 32 + quad * 8;
        short8 af = *(const short8*)(arow + k0);
        #pragma unroll
        for (int su = 0; su < 4; su++){
            short8 bf = *(const short8*)(Wt + (size_t)(n0 + su * 16 + col) * DD + k0);
            acc[su] = __builtin_amdgcn_mfma_f32_16x16x32_bf16(af, bf, acc[su], 0, 0, 0);
        }
    }

    #pragma unroll
    for (int su = 0; su < 4; su++){
        int n = n0 + su * 16 + col;
        float bz = bias[n];
        #pragma unroll
        for (int r = 0; r < 4; r++)
            C[(size_t)(m0 + quad * 4 + r) * M + n] = acc[su][r] + bz;
    }
}

// ---------------- fused QKV MFMA GEMM (bf16 A) ----------------
// r4/r5: V-transpose fused. z==2 writes V^T[n][m] directly as packed short4.
// For local layers A-rows are gathered via perm so m IS the sorted position.
struct QKV {
    const short* Wt[3];
    const float* bias[3];
    short*       Cb[2];    // Q, K row-major bf16 outs
    short*       VtOut;    // V^T [DD][NN] bf16
};
__global__ __launch_bounds__(256) void k_gemm_qkv(
        const short* __restrict__ A, QKV q, const int* __restrict__ permRow){
    int z = blockIdx.z;
    const short* Wt = q.Wt[z];
    const float* bias = q.bias[z];

    int tid = threadIdx.x;
    int w = tid >> 6, lane = tid & 63, quad = lane >> 4, col = lane & 15;
    int m0 = blockIdx.x * 64 + w * 16;
    int n0 = blockIdx.y * 64;

    int arowIdx = m0 + col;
    if (permRow) arowIdx = permRow[arowIdx];
    const short* arow = A + (size_t)arowIdx * DD;

    f32x4 acc[4];
    #pragma unroll
    for (int su = 0; su < 4; su++) acc[su] = (f32x4){0.f, 0.f, 0.f, 0.f};

    #pragma unroll
    for (int f = 0; f < 8; f++){
        int k0 = f * 32 + quad * 8;
        short8 af = *(const short8*)(arow + k0);
        #pragma unroll
        for (int su = 0; su < 4; su++){
            short8 bf = *(const short8*)(Wt + (size_t)(n0 + su * 16 + col) * DD + k0);
            acc[su] = __builtin_amdgcn_mfma_f32_16x16x32_bf16(af, bf, acc[su], 0, 0, 0);
        }
    }

    if (z == 2){
        // V^T: for fixed n, the 4 r-values are m-consecutive -> packed short4
        #pragma unroll
        for (int su = 0; su < 4; su++){
            int n = n0 + su * 16 + col;
            float bz = bias[n];
            short4v pk;
            #pragma unroll
            for (int r = 0; r < 4; r++) pk[r] = f2bf_s(acc[su][r] + bz);
            *(short4v*)(q.VtOut + (size_t)n * NN + m0 + quad * 4) = pk;
        }
    } else {
        short* Cb = q.Cb[z];
        #pragma unroll
        for (int su = 0; su < 4; su++){
            int n = n0 + su * 16 + col;
            float bz = bias[n];
            #pragma unroll
            for (int r = 0; r < 4; r++)
                Cb[(size_t)(m0 + quad * 4 + r) * DD + n] = f2bf_s(acc[su][r] + bz);
        }
    }
}

// ---------------- fused O-proj GEMM + residual + LayerNorm ----------------
// r6: template<MERGE>. MERGE=1 (global layers) fuses the old k_gmerge.
template<int MERGE>
__global__ __launch_bounds__(256) void k_gemm_o_ln(
        const short* __restrict__ A,
        const short* __restrict__ Opart, const float* __restrict__ lpart,
        const short* __restrict__ Wt, const float* __restrict__ bias,
        const float* __restrict__ g, const float* __restrict__ b,
        const float* __restrict__ pos,
        float* __restrict__ h, short* __restrict__ hbf, short* __restrict__ hpbf){
    __shared__ float t[16][258];                 // 16.5 KB
    __shared__ short Al[MERGE ? 16 * 256 : 1];   // 8 KB (MERGE only)
    __shared__ float lsum[MERGE ? 16 : 1];
    int tid = threadIdx.x;
    int w = tid >> 6, lane = tid & 63, quad = lane >> 4, col = lane & 15;
    int m0 = blockIdx.x * 16;
    int n0 = w * 64;

    const short* arow = A ? A + (size_t)(m0 + col) * DD : nullptr;

    if (MERGE){
        if (tid < 16){
            float l = 0.f;
            for (int s = 0; s < KS; s++) l += lpart[s * NN + m0 + tid];
            lsum[tid] = l;
        }
        __syncthreads();
        #pragma unroll
        for (int i = 0; i < 2; i++){
            int c = tid + i * 256;               // 512 chunks of short8
            int row = c >> 5, seg = c & 31;
            const short* src = Opart + (size_t)(m0 + row) * DD + seg * 8;
            float v[8] = {0.f,0.f,0.f,0.f,0.f,0.f,0.f,0.f};
            for (int s = 0; s < KS; s++){
                short8 o = *(const short8*)(src + (size_t)s * NN * DD);
                #pragma unroll
                for (int j = 0; j < 8; j++) v[j] += bf2f_s(o[j]);
            }
            float lr = lsum[row];
            short8 res;
            #pragma unroll
            for (int j = 0; j < 8; j++) res[j] = f2bf_s(v[j] / lr);
            *(short8*)&Al[(row << 8) + ((seg * 8) ^ ((row & 7) << 3))] = res;
        }
        __syncthreads();
    }

    f32x4 acc[4];
    #pragma unroll
    for (int su = 0; su < 4; su++) acc[su] = (f32x4){0.f, 0.f, 0.f, 0.f};

    #pragma unroll
    for (int f = 0; f < 8; f++){
        int k0 = f * 32 + quad * 8;
        short8 af;
        if (MERGE) af = *(const short8*)&Al[(col << 8) + (k0 ^ ((col & 7) << 3))];
        else       af = *(const short8*)(arow + k0);
        #pragma unroll
        for (int su = 0; su < 4; su++){
            short8 bf = *(const short8*)(Wt + (size_t)(n0 + su * 16 + col) * DD + k0);
            acc[su] = __builtin_amdgcn_mfma_f32_16x16x32_bf16(af, bf, acc[su], 0, 0, 0);
        }
    }

    #pragma unroll
    for (int su = 0; su < 4; su++){
        int n = n0 + su * 16 + col;
        float bz = bias[n];
        #pragma unroll
        for (int r = 0; r < 4; r++)
            t[quad * 4 + r][n] = acc[su][r] + bz;
    }
    __syncthreads();

    // ---- residual + LN: row = tid>>4, 16 lanes per row, 16 d's per lane
    int row = tid >> 4, l16 = tid & 15;
    int m = m0 + row;
    float v[16];
    float s = 0.f;
    #pragma unroll
    for (int j = 0; j < 16; j++){
        int d = l16 + j * 16;
        float vv = t[row][d] + h[(size_t)m * DD + d];
        v[j] = vv; s += vv;
    }
    #pragma unroll
    for (int off = 1; off < 16; off <<= 1) s += __shfl_xor(s, off);
    float mean = s * (1.0f / 256.0f);
    float s2 = 0.f;
    #pragma unroll
    for (int j = 0; j < 16; j++){ float c = v[j] - mean; s2 += c * c; }
    #pragma unroll
    for (int off = 1; off < 16; off <<= 1) s2 += __shfl_xor(s2, off);
    float rstd = rsqrtf(s2 * (1.0f / 256.0f) + 1e-5f);
    #pragma unroll
    for (int j = 0; j < 16; j++){
        int d = l16 + j * 16;
        float out = (v[j] - mean) * rstd * g[d] + b[d];
        size_t idx = (size_t)m * DD + d;
        h[idx] = out;
        hbf[idx] = f2bf_s(out);
        if (pos) hpbf[idx] = f2bf_s(out + pos[idx]);
    }
}

// ---------------- local attention v6 (r8-proven) ----------------
__global__ __launch_bounds__(256) void k_local_attn6(
        const short* __restrict__ Qs, const short* __restrict__ Ks, const short* __restrict__ Vts,
        const int* __restrict__ cstart, const int* __restrict__ perm, const int* __restrict__ inv,
        const int* __restrict__ rp, const int* __restrict__ e_dst, const int* __restrict__ e_typ,
        const float* __restrict__ eb, short* __restrict__ obbf){
    int c  = blockIdx.y;
    int hh = blockIdx.z;
    int cs0 = cstart[c], cs1 = cstart[c + 1];
    int Nc = cs1 - cs0;
    int p0 = blockIdx.x * 16;
    if (p0 >= Nc) return;
    int tid = threadIdx.x;
    int w = tid >> 6, lane = tid & 63, quad = lane >> 4, col = lane & 15;
    int nt  = (Nc + 15) >> 4;
    int nt2 = (Nc + 31) >> 5;

    __shared__ float sc[16][SCP];
    __shared__ float linv[16];
    __shared__ int qnode[16];

    if (tid < 16) qnode[tid] = (p0 + tid < Nc) ? perm[cs0 + p0 + tid] : -1;

    int qrow = cs0 + min(p0 + col, Nc - 1);
    short8 qf = *(const short8*)(Qs + (size_t)qrow * DD + hh * DHH + quad * 8);

    const float scale = 0.17677669529663687f; // 1/sqrt(32)

    for (int t = w; t < nt; t += 4){
        int kt = t * 16;
        int krow = cs0 + min(kt + col, Nc - 1);
        short8 kf = *(const short8*)(Ks + (size_t)krow * DD + hh * DHH + quad * 8);
        f32x4 s = __builtin_amdgcn_mfma_f32_16x16x32_bf16(qf, kf, (f32x4){0.f,0.f,0.f,0.f}, 0, 0, 0);
        #pragma unroll
        for (int r = 0; r < 4; r++)
            sc[quad * 4 + r][kt + col] = s[r] * scale;
    }
    __syncthreads();

    int qi = tid >> 4, l16 = tid & 15;
    {
        int n = qnode[qi];
        if (n >= 0){
            int re = rp[n + 1];
            for (int e2 = rp[n] + l16; e2 < re; e2 += 16){
                int dpos = inv[e_dst[e2]];
                if (dpos >= cs0 && dpos < cs1)
                    atomicAdd(&sc[qi][dpos - cs0], eb[e_typ[e2] * HH + hh]);
            }
        }
    }
    __syncthreads();

    {
        float lm = -1e30f;
        for (int m = l16; m < Nc; m += 16) lm = fmaxf(lm, sc[qi][m]);
        #pragma unroll
        for (int off = 1; off < 16; off <<= 1) lm = fmaxf(lm, __shfl_xor(lm, off));
        float ls = 0.f;
        for (int m = l16; m < Nc; m += 16){
            float e_ = __expf(sc[qi][m] - lm);
            sc[qi][m] = e_;
            ls += e_;
        }
        for (int m = (Nc & ~15) + l16; m < nt2 * 32; m += 16)
            if (m >= Nc) sc[qi][m] = 0.f;
        #pragma unroll
        for (int off = 1; off < 16; off <<= 1) ls += __shfl_xor(ls, off);
        if (l16 == 0) linv[qi] = 1.f / ls;
    }
    __syncthreads();

    f32x4 acc0 = (f32x4){0.f,0.f,0.f,0.f}, acc1 = (f32x4){0.f,0.f,0.f,0.f};
    for (int t2 = w; t2 < nt2; t2 += 4){
        int kt = t2 * 32;
        float4 pa = *(const float4*)&sc[col][kt + quad * 8];
        float4 pb = *(const float4*)&sc[col][kt + quad * 8 + 4];
        short8 pf;
        pf[0] = f2bf_s(pa.x); pf[1] = f2bf_s(pa.y); pf[2] = f2bf_s(pa.z); pf[3] = f2bf_s(pa.w);
        pf[4] = f2bf_s(pb.x); pf[5] = f2bf_s(pb.y); pf[6] = f2bf_s(pb.z); pf[7] = f2bf_s(pb.w);
        const short* vb0 = Vts + (size_t)(hh * DHH + col) * NN + cs0 + kt + quad * 8;
        short8 vf0 = *(const short8*)(vb0);
        short8 vf1 = *(const short8*)(vb0 + (size_t)16 * NN);
        acc0 = __builtin_amdgcn_mfma_f32_16x16x32_bf16(pf, vf0, acc0, 0, 0, 0);
        acc1 = __builtin_amdgcn_mfma_f32_16x16x32_bf16(pf, vf1, acc1, 0, 0, 0);
    }
    __syncthreads();   // all waves done READING sc -> safe to alias as pv
    {
        float (*pv)[16][33] = reinterpret_cast<float (*)[16][33]>(&sc[0][0]); // 8.45KB < 33KB
        #pragma unroll
        for (int r = 0; r < 4; r++){
            pv[w][quad * 4 + r][col]      = acc0[r];
            pv[w][quad * 4 + r][col + 16] = acc1[r];
        }
        __syncthreads();

        int q = tid >> 4, d0 = tid & 15;
        int n = qnode[q];
        #pragma unroll
        for (int half = 0; half < 2; half++){
            int dd = d0 + half * 16;
            float sum = pv[0][q][dd] + pv[1][q][dd] + pv[2][q][dd] + pv[3][q][dd];
            if (n >= 0) obbf[(size_t)n * DD + hh * DHH + dd] = f2bf_s(sum * linv[q]);
        }
    }
}

// ---------------- global attention v10+ (r8-proven, unchanged) ----------------
__global__ __launch_bounds__(256) void k_glob_mfma10(
        const short* __restrict__ Qb, const short* __restrict__ Kb,
        const short* __restrict__ Vt, const int* __restrict__ comm,
        short* __restrict__ Opart, float* __restrict__ lpart){
    int tid = threadIdx.x;
    int w = tid >> 6, lane = tid & 63, quad = lane >> 4, col = lane & 15;
    int qt = blockIdx.x * 64 + w * 16;
    int split = blockIdx.y;
    int ks0 = split * (NN / KS);   // 192 keys/split
    const int NT = NN / KS / 32;   // 6 key tiles

    __shared__ __align__(16) short Kl[32 * 256];  // 16.0 KB, XOR-swizzled
    __shared__ __align__(16) short Vl[256][40];   // 20.5 KB, V^T tile [d][key]
    __shared__ __align__(16) short Pl[4][16][40]; // 5.1 KB, per-wave P tiles

    short8 qf[8];
    #pragma unroll
    for (int f = 0; f < 8; f++)
        qf[f] = *(const short8*)(Qb + (size_t)(qt + col) * DD + f * 32 + quad * 8);

    int qc[4];
    #pragma unroll
    for (int r = 0; r < 4; r++) qc[r] = comm[qt + quad * 4 + r];

    f32x4 accO[16];
    #pragma unroll
    for (int dt = 0; dt < 16; dt++) accO[dt] = (f32x4){0.f, 0.f, 0.f, 0.f};
    float l_[4] = {0.f, 0.f, 0.f, 0.f};

    const float scale = 0.17677669529663687f; // 1/sqrt(32) per reference

    // per-thread staging geometry (chunk idx = tid + i*256)
    int ksg = tid & 31;            // K: 16B chunk within row
    int kr0 = tid >> 5;            // K: base row (+8 per i) -> (row&7) const per thread
    int ksw = (kr0 & 7) << 3;      // swizzle XOR, in shorts
    int vsg = tid & 3;             // V: chunk within d-row
    int vd0 = tid >> 2;            // V: base d (+64 per i)

    short8 kpre[4], vpre[4];
    #pragma unroll
    for (int i = 0; i < 4; i++){
        kpre[i] = *(const short8*)(Kb + (size_t)(ks0 + kr0 + 8 * i) * DD + ksg * 8);
        vpre[i] = *(const short8*)(Vt + (size_t)(vd0 + 64 * i) * NN + ks0 + vsg * 8);
    }
    int cm0n = comm[ks0 + col];
    int cm1n = comm[ks0 + 16 + col];

    for (int t = 0; t < NT; t++){
        int kt = ks0 + t * 32;
        __syncthreads();           // prev iteration's LDS reads complete
        #pragma unroll
        for (int i = 0; i < 4; i++){
            *(short8*)&Kl[(kr0 + 8 * i) * 256 + ((ksg * 8) ^ ksw)] = kpre[i];
            *(short8*)&Vl[vd0 + 64 * i][vsg * 8] = vpre[i];
        }
        __syncthreads();
        int cm0 = cm0n, cm1 = cm1n;
        if (t + 1 < NT){           // prefetch next tile; hides under MFMA below
            int kn = kt + 32;
            #pragma unroll
            for (int i = 0; i < 4; i++){
                kpre[i] = *(const short8*)(Kb + (size_t)(kn + kr0 + 8 * i) * DD + ksg * 8);
                vpre[i] = *(const short8*)(Vt + (size_t)(vd0 + 64 * i) * NN + kn + vsg * 8);
            }
            cm0n = comm[kn + col];
            cm1n = comm[kn + 16 + col];
        }

        // ---- S: 16 q x 32 keys from swizzled LDS frags
        f32x4 s0 = (f32x4){0.f,0.f,0.f,0.f}, s1 = (f32x4){0.f,0.f,0.f,0.f};
        int csw = (col & 7) << 3;  // (16+col)&7 == col&7
        #pragma unroll
        for (int f = 0; f < 8; f++){
            int cs = (f * 32 + quad * 8) ^ csw;
            short8 kf0 = *(const short8*)&Kl[col * 256 + cs];
            short8 kf1 = *(const short8*)&Kl[(16 + col) * 256 + cs];
            s0 = __builtin_amdgcn_mfma_f32_16x16x32_bf16(qf[f], kf0, s0, 0, 0, 0);
            s1 = __builtin_amdgcn_mfma_f32_16x16x32_bf16(qf[f], kf1, s1, 0, 0, 0);
        }

        #pragma unroll
        for (int r = 0; r < 4; r++){
            float p0 = (cm0 != qc[r]) ? __expf(s0[r] * scale) : 0.f;
            float p1 = (cm1 != qc[r]) ? __expf(s1[r] * scale) : 0.f;
            l_[r] += p0 + p1;
            int row = quad * 4 + r;
            Pl[w][row][col]      = f2bf_s(p0);
            Pl[w][row][col + 16] = f2bf_s(p1);
        }
        short8 pf = *(const short8*)(&Pl[w][col][quad * 8]);
        // ---- PV: V frags from LDS
        #pragma unroll
        for (int dt = 0; dt < 16; dt++){
            short8 vf = *(const short8*)&Vl[dt * 16 + col][quad * 8];
            accO[dt] = __builtin_amdgcn_mfma_f32_16x16x32_bf16(pf, vf, accO[dt], 0, 0, 0);
        }
    }

    #pragma unroll
    for (int r = 0; r < 4; r++){
        float vv = l_[r];
        #pragma unroll
        for (int off = 1; off < 16; off <<= 1) vv += __shfl_xor(vv, off);
        l_[r] = vv;
    }

    #pragma unroll
    for (int r = 0; r < 4; r++){
        int row = qt + quad * 4 + r;
        if (col == 0) lpart[split * NN + row] = l_[r];
        #pragma unroll
        for (int dt = 0; dt < 16; dt++)
            Opart[((size_t)split * NN + row) * DD + dt * 16 + col] = f2bf_s(accO[dt][r]);
    }
}

// ---------------- host ----------------
extern "C" void kernel_launch(void* const* d_in, const int* in_sizes, int n_in,
                              void* d_out, int out_size, void* d_ws, size_t ws_size,
                              hipStream_t stream){
    const float* x        = (const float*)d_in[0];
    const int*   ei       = (const int*)  d_in[1];
    const int*   et       = (const int*)  d_in[2];
    const float* pos      = (const float*)d_in[3];
    const int*   comm     = (const int*)  d_in[4];
    const float* emb_w    = (const float*)d_in[6];
    const float* emb_b    = (const float*)d_in[7];
    const float* loc_qw   = (const float*)d_in[8];
    const float* loc_qb   = (const float*)d_in[9];
    const float* loc_kw   = (const float*)d_in[10];
    const float* loc_kb   = (const float*)d_in[11];
    const float* loc_vw   = (const float*)d_in[12];
    const float* loc_vb   = (const float*)d_in[13];
    const float* loc_ow   = (const float*)d_in[14];
    const float* loc_ob   = (const float*)d_in[15];
    const float* loc_eb   = (const float*)d_in[16];
    const float* loc_ln_g = (const float*)d_in[17];
    const float* loc_ln_b = (const float*)d_in[18];
    const float* glob_qw  = (const float*)d_in[19];
    const float* glob_qb  = (const float*)d_in[20];
    const float* glob_kw  = (const float*)d_in[21];
    const float* glob_kb  = (const float*)d_in[22];
    const float* glob_vw  = (const float*)d_in[23];
    const float* glob_vb  = (const float*)d_in[24];
    const float* glob_ow  = (const float*)d_in[25];
    const float* glob_ob  = (const float*)d_in[26];
    const float* glob_ln_g= (const float*)d_in[27];
    const float* glob_ln_b= (const float*)d_in[28];
    const float* out_w    = (const float*)d_in[29];
    const float* out_b    = (const float*)d_in[30];

    float* h    = (float*)d_ws;           // NN*DD f32
    float* lpart= h + NN * DD;            // KS*NN
    int* cnt    = (int*)(lpart + KS * NN);
    int* cur    = cnt + NN;
    int* ccnt   = cur + NN;
    int* ccur   = ccnt + NC;
    int* cstart = ccur + NC;
    int* rp     = cstart + NC + 1;
    int* perm   = rp + NN + 1;
    int* inv    = perm + NN;
    int* e_dst  = inv + NN;
    int* e_typ  = e_dst + EE;
    short* Qbf  = (short*)(((uintptr_t)(e_typ + EE) + 15) & ~(uintptr_t)15);
    short* Kbf  = Qbf + NN * DD;
    short* Vt   = Kbf + NN * DD;          // [DD][NN]
    short* WtAll= Vt + (size_t)DD * NN;   // 16*65536 + 131072 shorts
    short* Qs   = WtAll + 16 * DD * DD + DD * OO;  // sorted bf16 Q [NN][DD]
    short* Ks2  = Qs + (size_t)NN * DD;            // sorted bf16 K
    short* Vts  = Ks2 + (size_t)NN * DD;           // sorted V^T [DD][NN]
    short* Opart= Vts + (size_t)DD * NN;           // KS*NN*DD bf16
    short* hbf  = Opart + (size_t)KS * NN * DD;    // bf16(h)
    short* hpbf = hbf + (size_t)NN * DD;           // bf16(h+pos)
    short* obbf = hpbf + (size_t)NN * DD;          // bf16 attn output (local GEMM A)

    PRE p;
    const float* wsrc[NW] = {
        loc_qw, loc_kw, loc_vw, loc_ow,
        loc_qw + DD * DD, loc_kw + DD * DD, loc_vw + DD * DD, loc_ow + DD * DD,
        glob_qw, glob_kw, glob_vw, glob_ow,
        glob_qw + DD * DD, glob_kw + DD * DD, glob_vw + DD * DD, glob_ow + DD * DD,
        out_w };
    for (int i = 0; i < NW; i++){
        p.src[i] = wsrc[i];
        p.dst[i] = WtAll + (size_t)i * DD * DD;
        p.M[i]   = (i == 16) ? OO : DD;
    }
    p.x = x; p.emb_w = emb_w; p.emb_b = emb_b; p.pos = pos;
    p.h = h; p.hbf = hbf; p.hpbf = hpbf;
    p.ei = ei; p.comm = comm; p.cnt = cnt; p.ccnt = ccnt;

    short* WtLQ[2] = { WtAll + 0 * DD * DD, WtAll + 4 * DD * DD };
    short* WtLK[2] = { WtAll + 1 * DD * DD, WtAll + 5 * DD * DD };
    short* WtLV[2] = { WtAll + 2 * DD * DD, WtAll + 6 * DD * DD };
    short* WtLO[2] = { WtAll + 3 * DD * DD, WtAll + 7 * DD * DD };
    short* WtGQ[2] = { WtAll + 8 * DD * DD, WtAll + 12 * DD * DD };
    short* WtGK[2] = { WtAll + 9 * DD * DD, WtAll + 13 * DD * DD };
    short* WtGV[2] = { WtAll + 10 * DD * DD, WtAll + 14 * DD * DD };
    short* WtGO[2] = { WtAll + 11 * DD * DD, WtAll + 15 * DD * DD };
    short* WtOut   = WtAll + 16 * DD * DD;

    (void)hipMemsetAsync(cnt, 0, sizeof(int) * (2 * NN + 2 * NC), stream);

    k_preproc<<<PRE_EMBED + PRE_WT + PRE_CNT, 256, 0, stream>>>(p);
    k_scan2<<<1, 256, 0, stream>>>(cnt, rp, ccnt, cstart);
    k_fill2<<<EE / 256, 256, 0, stream>>>(ei, et, rp, cur, e_dst, e_typ,
                                          comm, cstart, ccur, perm, inv);

    for (int l = 0; l < 2; l++){
        QKV q;
        q.Wt[0] = WtLQ[l]; q.Wt[1] = WtLK[l]; q.Wt[2] = WtLV[l];
        q.bias[0] = loc_qb + l * DD; q.bias[1] = loc_kb + l * DD; q.bias[2] = loc_vb + l * DD;
        q.Cb[0] = Qs; q.Cb[1] = Ks2;
        q.VtOut = Vts;
        // A-rows permuted -> outputs land directly in sorted space
        k_gemm_qkv<<<dim3(NN / 64, DD / 64, 3), 256, 0, stream>>>(hpbf, q, perm);
        k_local_attn6<<<dim3(NCMAX / 16, NC, HH), 256, 0, stream>>>(
            Qs, Ks2, Vts, cstart, perm, inv, rp, e_dst, e_typ,
            loc_eb + l * NETT * HH, obbf);
        k_gemm_o_ln<0><<<NN / 16, 256, 0, stream>>>(
            obbf, nullptr, nullptr,
            WtLO[l], loc_ob + l * DD, loc_ln_g + l * DD, loc_ln_b + l * DD,
            (l == 0) ? pos : nullptr, h, hbf, hpbf);
    }

    for (int g = 0; g < 2; g++){
        QKV q;
        q.Wt[0] = WtGQ[g]; q.Wt[1] = WtGK[g]; q.Wt[2] = WtGV[g];
        q.bias[0] = glob_qb + g * DD; q.bias[1] = glob_kb + g * DD; q.bias[2] = glob_vb + g * DD;
        q.Cb[0] = Qbf; q.Cb[1] = Kbf;
        q.VtOut = Vt;
        k_gemm_qkv<<<dim3(NN / 64, DD / 64, 3), 256, 0, stream>>>(hbf, q, nullptr);
        k_glob_mfma10<<<dim3(NN / 64, KS), 256, 0, stream>>>(Qbf, Kbf, Vt, comm, Opart, lpart);
        k_gemm_o_ln<1><<<NN / 16, 256, 0, stream>>>(
            nullptr, Opart, lpart,
            WtGO[g], glob_ob + g * DD, glob_ln_g + g * DD, glob_ln_b + g * DD,
            nullptr, h, hbf, nullptr);
    }

    k_gemm_mfma<OO><<<dim3(NN / 64, OO / 64), 256, 0, stream>>>(hbf, WtOut, out_b, (float*)d_out);
}